// Round 7
// baseline (3165.315 us; speedup 1.0000x reference)
//
#include <hip/hip_runtime.h>
#include <stdint.h>

#define BB 32
#define LL 1024
#define NW 512
#define HH 768
#define HID 384
#define G4 1536   // 4*HID
#define EE 4
#define DLL 128
#define GIN 896   // H+DL
#define CWG 12    // column-group WGs per direction
#define WGC 32    // h-cols per WG
#define HPAD 392  // padded LDS row stride (shorts)

typedef __attribute__((ext_vector_type(8))) short short8;
typedef __attribute__((ext_vector_type(4))) float f32x4;
typedef __attribute__((ext_vector_type(2))) float f32x2;
typedef __attribute__((ext_vector_type(4))) unsigned int u32x4;
typedef __attribute__((ext_vector_type(2))) unsigned int u32x2;

__device__ __forceinline__ float bf2f(short s){
  union { unsigned int u; float f; } v; v.u = ((unsigned int)(unsigned short)s) << 16; return v.f;
}
__device__ __forceinline__ short f2bf(float f){
  union { float f; unsigned int u; } v; v.f = f;
  unsigned int r = v.u + 0x7fffu + ((v.u >> 16) & 1u);
  return (short)(r >> 16);
}
__device__ __forceinline__ float sigm(float x){ return 1.f / (1.f + __expf(-x)); }
__device__ __forceinline__ float ftanh(float x){ float e = __expf(2.f * x); return 1.f - 2.f / (e + 1.f); }

__device__ __forceinline__ void gload16(const void* g, void* l){
  __builtin_amdgcn_global_load_lds(
      (const __attribute__((address_space(1))) unsigned int*)g,
      (__attribute__((address_space(3))) unsigned int*)l, 16, 0, 0);
}

// ---------------- f32 -> bf16 convert ----------------
__global__ void k_f2bf(const float* in, short* out, int n){
  int i = blockIdx.x * blockDim.x + threadIdx.x;
  int st = gridDim.x * blockDim.x;
  for (; i < n; i += st) out[i] = f2bf(in[i]);
}

// ---------------- segment mean pooling ----------------
__global__ __launch_bounds__(256) void k_segmean(const float* __restrict__ tok,
                                                 const int* __restrict__ wmap,
                                                 short* __restrict__ we_bf){
  int blk = blockIdx.x;
  int b = blk >> 9;          // / NW
  int w = blk & 511;
  const int* m = wmap + b * LL;
  int lo = 0, hi = LL;
  while (lo < hi){ int mid = (lo + hi) >> 1; if (m[mid] < w) lo = mid + 1; else hi = mid; }
  int s = lo;
  int lo2 = s, hi2 = LL;
  while (lo2 < hi2){ int mid = (lo2 + hi2) >> 1; if (m[mid] <= w) lo2 = mid + 1; else hi2 = mid; }
  int e = lo2;
  float cnt = (float)(e - s);
  float denom = fmaxf(cnt, 1.f);
  for (int j = threadIdx.x; j < HH; j += 256){
    float acc = 0.f;
    for (int r = s; r < e; ++r) acc += tok[((size_t)b * LL + r) * HH + j];
    we_bf[((size_t)b * NW + w) * HH + j] = f2bf(acc / denom);
  }
}

// ---------------- GEMM: C[M,N] = A[M,K](bf16) * W[N,K]^T(bf16) + b1[n] + b2[n] ----------------
__global__ __launch_bounds__(256) void k_gemm_bt(const short* __restrict__ Abf,
                                                 const short* __restrict__ Wbf,
                                                 const float* __restrict__ b1,
                                                 const float* __restrict__ b2,
                                                 float* __restrict__ Cf,
                                                 int M, int N, int K){
  __shared__ __attribute__((aligned(16))) short As[128 * 32];
  __shared__ __attribute__((aligned(16))) short Bs[128 * 32];
  int ntiles = N >> 7;
  int m0 = (blockIdx.x / ntiles) << 7;
  int n0 = (blockIdx.x % ntiles) << 7;
  int tid = threadIdx.x, lane = tid & 63, wv = tid >> 6;
  int wm = (wv >> 1) << 6, wn = (wv & 1) << 6;
  f32x4 acc[4][4] = {};
  for (int kk = 0; kk < K; kk += 32){
#pragma unroll
    for (int q = 0; q < 2; ++q){
      int e = q * 256 + tid;        // 16B granule: row = e/4, col = (e&3)*8 shorts
      int row = e >> 2, col = (e & 3) << 3;
      gload16(Abf + (size_t)(m0 + row) * K + kk + col, As + e * 8);
      gload16(Wbf + (size_t)(n0 + row) * K + kk + col, Bs + e * 8);
    }
    __syncthreads();
    short8 af[4], bfr[4];
#pragma unroll
    for (int x = 0; x < 4; ++x){
      af[x]  = *(const short8*)(As + (wm + x * 16 + (lane & 15)) * 32 + ((lane >> 4) << 3));
      bfr[x] = *(const short8*)(Bs + (wn + x * 16 + (lane & 15)) * 32 + ((lane >> 4) << 3));
    }
#pragma unroll
    for (int x = 0; x < 4; ++x)
#pragma unroll
      for (int y = 0; y < 4; ++y)
        acc[x][y] = __builtin_amdgcn_mfma_f32_16x16x32_bf16(af[x], bfr[y], acc[x][y], 0, 0, 0);
    __syncthreads();
  }
#pragma unroll
  for (int x = 0; x < 4; ++x)
#pragma unroll
    for (int y = 0; y < 4; ++y)
#pragma unroll
      for (int i = 0; i < 4; ++i){
        int mm = m0 + wm + x * 16 + ((lane >> 4) << 2) + i;
        int nn = n0 + wn + y * 16 + (lane & 15);
        Cf[(size_t)mm * N + nn] = acc[x][y][i] + b1[nn] + b2[nn];
      }
}

// ---------------- BiLSTM: persistent, TAG-IN-DATA sync (no flags) ----------------
// 12 WGs/dir x 512 threads. h cells stored as u32 = (bf16<<16) | step_tag.
// Consumers load + tag-check + retry: one MALL hop replaces store-ack+flag+poll.
// Overwrite safety: staging h(t) complete => all WGs stored h(t) => all consumed
// h(t-1) => buf[(t+1)&1] (== buf[(t-1)&1]) is drained before anyone writes h(t+1).
__global__ __launch_bounds__(512) void k_lstm(const float* __restrict__ xg_f,
                                              const float* __restrict__ xg_b,
                                              const short* __restrict__ whh_f,
                                              const short* __restrict__ whh_b,
                                              unsigned int* __restrict__ hbuf,
                                              short* __restrict__ hcat){
  int bx = blockIdx.x;
  int dir = bx / CWG;
  int cg  = bx % CWG;
  int tid = threadIdx.x, lane = tid & 63, wv = tid >> 6;
  int q = lane >> 4, fr = lane & 15;
  int g = wv >> 1, nh = wv & 1;                // gate, 16-col half of WG's 32 cols
  int jbase = g * HID + cg * WGC + nh * 16;
  const float* xg  = dir ? xg_b : xg_f;
  const short* whh = dir ? whh_b : whh_f;

  // resident Whh B-fragments: 16 gate-rows x K=384 -> 12 k-steps, 48 VGPRs
  short8 bfrag[12];
  {
    const short* wr = whh + (size_t)(jbase + fr) * HID + q * 8;
#pragma unroll
    for (int ks = 0; ks < 12; ++ks) bfrag[ks] = *(const short8*)(wr + ks * 32);
  }

  __shared__ __attribute__((aligned(16))) short hs[32 * HPAD];  // staged h(t-1), 24.5 KB
  __shared__ float pre[4][BB][34];                              // preacts, <=2-way conflicts

  float c0 = 0.f, c1 = 0.f;
  int eb = tid >> 4, ecp = (tid & 15) * 2;   // elementwise: (b=eb, cols ecp,ecp+1)
  unsigned int* hbD = hbuf + (size_t)dir * 2 * BB * HID;
  // staging split: thread covers 24 consecutive cells
  int sr = (tid * 24) / HID, sc = (tid * 24) % HID;

  float xgv[8], nxg[8];
  {
    int t0a = dir ? (NW - 1) : 0;
#pragma unroll
    for (int i = 0; i < 4; ++i){
      xgv[i]     = xg[((size_t)(q * 4 + i) * NW + t0a) * G4 + jbase + fr];
      xgv[4 + i] = xg[((size_t)(16 + q * 4 + i) * NW + t0a) * G4 + jbase + fr];
    }
  }

  for (int t = 0; t < NW; ++t){
    int t_act = dir ? (NW - 1 - t) : t;
    f32x4 acc0 = {}, acc1 = {}, acc0b = {}, acc1b = {};
    u32x4 d0, d1, d2, d3, d4, d5;
    if (t > 0){
      // tagged stage of h(t-1): retry until all 24 tags == t
      unsigned int expect = (unsigned int)t & 0xffffu;
      const unsigned int* hp = hbD + (size_t)((t - 1) & 1) * BB * HID + tid * 24;
      for (;;){
        asm volatile("global_load_dwordx4 %0, %1, off sc0 sc1" : "=v"(d0) : "v"(hp +  0) : "memory");
        asm volatile("global_load_dwordx4 %0, %1, off sc0 sc1" : "=v"(d1) : "v"(hp +  4) : "memory");
        asm volatile("global_load_dwordx4 %0, %1, off sc0 sc1" : "=v"(d2) : "v"(hp +  8) : "memory");
        asm volatile("global_load_dwordx4 %0, %1, off sc0 sc1" : "=v"(d3) : "v"(hp + 12) : "memory");
        asm volatile("global_load_dwordx4 %0, %1, off sc0 sc1" : "=v"(d4) : "v"(hp + 16) : "memory");
        asm volatile("global_load_dwordx4 %0, %1, off sc0 sc1" : "=v"(d5) : "v"(hp + 20) : "memory");
        asm volatile("s_waitcnt vmcnt(0)" ::: "memory");
        __builtin_amdgcn_sched_barrier(0);
#define TAGBAD(dv) (((dv[0] ^ expect) | (dv[1] ^ expect) | (dv[2] ^ expect) | (dv[3] ^ expect)) & 0xffffu)
        unsigned int bad = TAGBAD(d0) | TAGBAD(d1) | TAGBAD(d2) | TAGBAD(d3) | TAGBAD(d4) | TAGBAD(d5);
#undef TAGBAD
        if (__all(bad == 0)) break;
        __builtin_amdgcn_s_sleep(1);
      }
      // strip tags (2 cells -> 1 u32 of 2 bf16) and write LDS
      unsigned int pk0  = (d0[0] >> 16) | (d0[1] & 0xffff0000u);
      unsigned int pk1  = (d0[2] >> 16) | (d0[3] & 0xffff0000u);
      unsigned int pk2  = (d1[0] >> 16) | (d1[1] & 0xffff0000u);
      unsigned int pk3  = (d1[2] >> 16) | (d1[3] & 0xffff0000u);
      unsigned int pk4  = (d2[0] >> 16) | (d2[1] & 0xffff0000u);
      unsigned int pk5  = (d2[2] >> 16) | (d2[3] & 0xffff0000u);
      unsigned int pk6  = (d3[0] >> 16) | (d3[1] & 0xffff0000u);
      unsigned int pk7  = (d3[2] >> 16) | (d3[3] & 0xffff0000u);
      unsigned int pk8  = (d4[0] >> 16) | (d4[1] & 0xffff0000u);
      unsigned int pk9  = (d4[2] >> 16) | (d4[3] & 0xffff0000u);
      unsigned int pk10 = (d5[0] >> 16) | (d5[1] & 0xffff0000u);
      unsigned int pk11 = (d5[2] >> 16) | (d5[3] & 0xffff0000u);
      u32x4 P0 = {pk0, pk1, pk2, pk3};
      u32x4 P1 = {pk4, pk5, pk6, pk7};
      u32x4 P2 = {pk8, pk9, pk10, pk11};
      short* dst = hs + sr * HPAD + sc;
      *(u32x4*)(dst)      = P0;
      *(u32x4*)(dst + 8)  = P1;
      *(u32x4*)(dst + 16) = P2;
      if (cg == 0){
        // stager writes hcat for step t-1 (off the critical recurrence path)
        int tprev = dir ? (NW - t) : (t - 1);
        short* dh = hcat + ((size_t)sr * NW + tprev) * HH + dir * HID + sc;
        *(u32x4*)(dh)      = P0;
        *(u32x4*)(dh + 8)  = P1;
        *(u32x4*)(dh + 16) = P2;
      }
#pragma unroll
      for (int i = 0; i < 8; ++i) xgv[i] = nxg[i];
    }
    asm volatile("s_waitcnt lgkmcnt(0)" ::: "memory");
    __builtin_amdgcn_s_barrier();              // barrier A: staging visible
    __builtin_amdgcn_sched_barrier(0);
    // prefetch next step's xg (flies under MFMA/elementwise; drained by next retry)
    if (t + 1 < NW){
      int tn = dir ? (NW - 2 - t) : (t + 1);
#pragma unroll
      for (int i = 0; i < 4; ++i){
        nxg[i]     = xg[((size_t)(q * 4 + i) * NW + tn) * G4 + jbase + fr];
        nxg[4 + i] = xg[((size_t)(16 + q * 4 + i) * NW + tn) * G4 + jbase + fr];
      }
    }
    if (t > 0){
      const short* hrow0 = hs + fr * HPAD + q * 8;
      const short* hrow1 = hs + (fr + 16) * HPAD + q * 8;
#pragma unroll
      for (int ks = 0; ks < 6; ++ks){
        acc0  = __builtin_amdgcn_mfma_f32_16x16x32_bf16(*(const short8*)(hrow0 + ks * 32), bfrag[ks], acc0, 0, 0, 0);
        acc1  = __builtin_amdgcn_mfma_f32_16x16x32_bf16(*(const short8*)(hrow1 + ks * 32), bfrag[ks], acc1, 0, 0, 0);
      }
#pragma unroll
      for (int ks = 6; ks < 12; ++ks){
        acc0b = __builtin_amdgcn_mfma_f32_16x16x32_bf16(*(const short8*)(hrow0 + ks * 32), bfrag[ks], acc0b, 0, 0, 0);
        acc1b = __builtin_amdgcn_mfma_f32_16x16x32_bf16(*(const short8*)(hrow1 + ks * 32), bfrag[ks], acc1b, 0, 0, 0);
      }
      acc0 += acc0b; acc1 += acc1b;
    }
#pragma unroll
    for (int i = 0; i < 4; ++i){
      int b0 = q * 4 + i;
      pre[g][b0][nh * 16 + fr]      = acc0[i] + xgv[i];
      pre[g][b0 + 16][nh * 16 + fr] = acc1[i] + xgv[4 + i];
    }
    asm volatile("s_waitcnt lgkmcnt(0)" ::: "memory");
    __builtin_amdgcn_s_barrier();              // barrier B: preacts ready
    __builtin_amdgcn_sched_barrier(0);
    // elementwise LSTM cell: (eb, ecp) and (eb, ecp+1)
    f32x2 gi2 = *(f32x2*)&pre[0][eb][ecp];
    f32x2 gf2 = *(f32x2*)&pre[1][eb][ecp];
    f32x2 gg2 = *(f32x2*)&pre[2][eb][ecp];
    f32x2 go2 = *(f32x2*)&pre[3][eb][ecp];
    c0 = sigm(gf2.x) * c0 + sigm(gi2.x) * ftanh(gg2.x);
    float h0 = sigm(go2.x) * ftanh(c0);
    c1 = sigm(gf2.y) * c1 + sigm(gi2.y) * ftanh(gg2.y);
    float h1 = sigm(go2.y) * ftanh(c1);
    unsigned int us0 = (unsigned int)(unsigned short)f2bf(h0);
    unsigned int us1 = (unsigned int)(unsigned short)f2bf(h1);
    unsigned int tagw = (unsigned int)(t + 1) & 0xffffu;
    u32x2 wvx = {(us0 << 16) | tagw, (us1 << 16) | tagw};
    unsigned int* hw = hbD + (size_t)(t & 1) * BB * HID + eb * HID + cg * WGC + ecp;
    asm volatile("global_store_dwordx2 %0, %1, off sc0 sc1" :: "v"(hw), "v"(wvx) : "memory");
    if (t == NW - 1){   // final step's h never staged by anyone — producers write hcat
      unsigned int hc = us0 | (us1 << 16);
      *(unsigned int*)(hcat + ((size_t)eb * NW + t_act) * HH + dir * HID + cg * WGC + ecp) = hc;
    }
    // no end barrier: stores propagate while loop wraps; consumers retry on tags
  }
}

// ---------------- gate MLP + softmax (per batch row) ----------------
__global__ __launch_bounds__(256) void k_gate(const float* __restrict__ tok,
                                              const int* __restrict__ lids,
                                              const float* __restrict__ ltab,
                                              const float* __restrict__ W1,
                                              const float* __restrict__ b1v,
                                              const float* __restrict__ W2,
                                              const float* __restrict__ b2v,
                                              float* __restrict__ gate){
  __shared__ float gin[GIN];
  __shared__ float hid[HH];
  __shared__ float pr[EE];
  int b = blockIdx.x, tid = threadIdx.x;
  int lid = lids[b];
  for (int i = tid; i < GIN; i += 256)
    gin[i] = (i < HH) ? tok[(size_t)b * LL * HH + i] : ltab[lid * DLL + (i - HH)];
  __syncthreads();
  for (int j = tid; j < HH; j += 256){
    float a = b1v[j];
    const float* wr = W1 + (size_t)j * GIN;
    for (int k = 0; k < GIN; ++k) a += gin[k] * wr[k];
    hid[j] = fmaxf(a, 0.f);
  }
  __syncthreads();
  int wv = tid >> 6, lane = tid & 63;
  if (wv < EE){
    float p = 0.f;
    for (int k = lane; k < HH; k += 64) p += hid[k] * W2[wv * HH + k];
#pragma unroll
    for (int off = 32; off; off >>= 1) p += __shfl_down(p, off);
    if (lane == 0) pr[wv] = p + b2v[wv];
  }
  __syncthreads();
  if (tid == 0){
    float mx = fmaxf(fmaxf(pr[0], pr[1]), fmaxf(pr[2], pr[3]));
    float s = 0.f, ex[EE];
    for (int e2 = 0; e2 < EE; ++e2){ ex[e2] = __expf(pr[e2] - mx); s += ex[e2]; }
    for (int e2 = 0; e2 < EE; ++e2) gate[b * EE + e2] = ex[e2] / s;
  }
}

// ---------------- head precompute: A = headW @ proj_W, c = headW.proj_b + head_b ----------------
__global__ __launch_bounds__(256) void k_headpre(const float* __restrict__ efW,
                                                 const float* __restrict__ efb,
                                                 const float* __restrict__ edW,
                                                 const float* __restrict__ edb,
                                                 const float* __restrict__ projW,
                                                 const float* __restrict__ projb,
                                                 float* __restrict__ Acomb,
                                                 float* __restrict__ Ccomb){
  int head = blockIdx.x >> 2, e2 = blockIdx.x & 3, tid = threadIdx.x;
  const float* Wv = head ? edW : efW;
  const float* bv = head ? edb : efb;
  __shared__ float wrow[HH];
  for (int i = tid; i < HH; i += 256) wrow[i] = Wv[e2 * HH + i];
  __syncthreads();
  for (int c = tid; c < HH; c += 256){
    float a = 0.f;
    for (int h2 = 0; h2 < HH; ++h2) a += wrow[h2] * projW[(size_t)h2 * HH + c];
    Acomb[(head * 4 + e2) * HH + c] = a;
  }
  int wv = tid >> 6, lane = tid & 63;
  if (wv == 0){
    float p = 0.f;
    for (int k = lane; k < HH; k += 64) p += wrow[k] * projb[k];
#pragma unroll
    for (int off = 32; off; off >>= 1) p += __shfl_down(p, off);
    if (lane == 0) Ccomb[head * 4 + e2] = p + bv[e2];
  }
}

// ---------------- fused expert heads: out = sum_e gate * (hcat.A_e + c_e) ----------------
__global__ __launch_bounds__(256) void k_heads(const short* __restrict__ hcat,
                                               const float* __restrict__ Acomb,
                                               const float* __restrict__ Ccomb,
                                               const float* __restrict__ gate,
                                               float* __restrict__ outp){
  __shared__ float Al[8 * HH];   // 24 KB
  int tid = threadIdx.x;
  for (int i = tid; i < 8 * HH; i += 256) Al[i] = Acomb[i];
  __syncthreads();
  int wv = tid >> 6, lane = tid & 63;
  int bw = blockIdx.x * 4 + wv;        // = b*512 + w
  const short* hr = hcat + (size_t)bw * HH;
  float hv[12];
#pragma unroll
  for (int j = 0; j < 12; ++j) hv[j] = bf2f(hr[lane + 64 * j]);
  float dsum[8];
#pragma unroll
  for (int v = 0; v < 8; ++v){
    float p = 0.f;
#pragma unroll
    for (int j = 0; j < 12; ++j) p += hv[j] * Al[v * HH + lane + 64 * j];
#pragma unroll
    for (int off = 32; off; off >>= 1) p += __shfl_xor(p, off);
    dsum[v] = p;
  }
  if (lane == 0){
    int b = bw >> 9;
    float fx = 0.f, du = 0.f;
#pragma unroll
    for (int e2 = 0; e2 < 4; ++e2){
      float g = gate[b * 4 + e2];
      fx += g * (dsum[e2]     + Ccomb[e2]);
      du += g * (dsum[4 + e2] + Ccomb[4 + e2]);
    }
    outp[bw] = fx;
    outp[BB * NW + bw] = du;
  }
}

extern "C" void kernel_launch(void* const* d_in, const int* in_sizes, int n_in,
                              void* d_out, int out_size, void* d_ws, size_t ws_size,
                              hipStream_t stream){
  const float* tok   = (const float*)d_in[0];
  const int*   wmap  = (const int*)d_in[1];
  const int*   lids  = (const int*)d_in[2];
  const float* Wih_f = (const float*)d_in[3];
  const float* Whh_f = (const float*)d_in[4];
  const float* bih_f = (const float*)d_in[5];
  const float* bhh_f = (const float*)d_in[6];
  const float* Wih_b = (const float*)d_in[7];
  const float* Whh_b = (const float*)d_in[8];
  const float* bih_b = (const float*)d_in[9];
  const float* bhh_b = (const float*)d_in[10];
  const float* projW = (const float*)d_in[11];
  const float* projb = (const float*)d_in[12];
  const float* ltab  = (const float*)d_in[13];
  const float* gW1   = (const float*)d_in[14];
  const float* gb1   = (const float*)d_in[15];
  const float* gW2   = (const float*)d_in[16];
  const float* gb2   = (const float*)d_in[17];
  const float* efW   = (const float*)d_in[18];
  const float* efb   = (const float*)d_in[19];
  const float* edW   = (const float*)d_in[20];
  const float* edb   = (const float*)d_in[21];
  float* outp = (float*)d_out;

  char* ws = (char*)d_ws;
  size_t off = 0;
  auto alloc = [&](size_t bytes) -> char* {
    char* p = ws + off;
    off = (off + bytes + 255) & ~(size_t)255;
    return p;
  };
  short* we_bf   = (short*)alloc((size_t)BB * NW * HH * 2);
  short* wihf_bf = (short*)alloc((size_t)G4 * HH * 2);
  short* wihb_bf = (short*)alloc((size_t)G4 * HH * 2);
  short* whhf_bf = (short*)alloc((size_t)G4 * HID * 2);
  short* whhb_bf = (short*)alloc((size_t)G4 * HID * 2);
  float* xg_f    = (float*)alloc((size_t)BB * NW * G4 * 4);
  float* xg_b    = (float*)alloc((size_t)BB * NW * G4 * 4);
  short* hcat    = (short*)alloc((size_t)BB * NW * HH * 2);
  unsigned int* hbuf = (unsigned int*)alloc((size_t)2 * 2 * BB * HID * 4);  // tagged
  float* gateb   = (float*)alloc((size_t)BB * EE * 4);
  float* Acomb   = (float*)alloc((size_t)8 * HH * 4);
  float* Ccomb   = (float*)alloc((size_t)8 * 4);

  k_f2bf<<<1024, 256, 0, stream>>>(Wih_f, wihf_bf, G4 * HH);
  k_f2bf<<<1024, 256, 0, stream>>>(Wih_b, wihb_bf, G4 * HH);
  k_f2bf<<<512, 256, 0, stream>>>(Whh_f, whhf_bf, G4 * HID);
  k_f2bf<<<512, 256, 0, stream>>>(Whh_b, whhb_bf, G4 * HID);
  k_segmean<<<BB * NW, 256, 0, stream>>>(tok, wmap, we_bf);
  k_gemm_bt<<<(BB * NW / 128) * (G4 / 128), 256, 0, stream>>>(we_bf, wihf_bf, bih_f, bhh_f, xg_f, BB * NW, G4, HH);
  k_gemm_bt<<<(BB * NW / 128) * (G4 / 128), 256, 0, stream>>>(we_bf, wihb_bf, bih_b, bhh_b, xg_b, BB * NW, G4, HH);
  k_gate<<<BB, 256, 0, stream>>>(tok, lids, ltab, gW1, gb1, gW2, gb2, gateb);
  k_headpre<<<8, 256, 0, stream>>>(efW, efb, edW, edb, projW, projb, Acomb, Ccomb);
  k_lstm<<<2 * CWG, 512, 0, stream>>>(xg_f, xg_b, whhf_bf, whhb_bf, hbuf, hcat);
  k_heads<<<(BB * NW) / 4, 256, 0, stream>>>(hcat, Acomb, Ccomb, gateb, outp);
}

// Round 8
// 2579.780 us; speedup vs baseline: 1.2270x; 1.2270x over previous
//
#include <hip/hip_runtime.h>
#include <stdint.h>

#define BB 32
#define LL 1024
#define NW 512
#define HH 768
#define HID 384
#define G4 1536   // 4*HID
#define EE 4
#define DLL 128
#define GIN 896   // H+DL
#define CWG 12    // column-group WGs per direction
#define WGC 32    // h-cols per WG
#define HPAD 392  // padded LDS row stride (shorts): balanced-8 banks for b128 MFMA reads

typedef __attribute__((ext_vector_type(8))) short short8;
typedef __attribute__((ext_vector_type(4))) float f32x4;
typedef __attribute__((ext_vector_type(4))) unsigned int u32x4;
typedef __attribute__((ext_vector_type(2))) unsigned int u32x2;

__device__ __forceinline__ float bf2f(short s){
  union { unsigned int u; float f; } v; v.u = ((unsigned int)(unsigned short)s) << 16; return v.f;
}
__device__ __forceinline__ short f2bf(float f){
  union { float f; unsigned int u; } v; v.f = f;
  unsigned int r = v.u + 0x7fffu + ((v.u >> 16) & 1u);
  return (short)(r >> 16);
}
__device__ __forceinline__ float sigm(float x){ return 1.f / (1.f + __expf(-x)); }
__device__ __forceinline__ float ftanh(float x){ float e = __expf(2.f * x); return 1.f - 2.f / (e + 1.f); }

__device__ __forceinline__ void gload16(const void* g, void* l){
  __builtin_amdgcn_global_load_lds(
      (const __attribute__((address_space(1))) unsigned int*)g,
      (__attribute__((address_space(3))) unsigned int*)l, 16, 0, 0);
}

// ---------------- f32 -> bf16 convert ----------------
__global__ void k_f2bf(const float* in, short* out, int n){
  int i = blockIdx.x * blockDim.x + threadIdx.x;
  int st = gridDim.x * blockDim.x;
  for (; i < n; i += st) out[i] = f2bf(in[i]);
}

// ---------------- segment mean pooling ----------------
__global__ __launch_bounds__(256) void k_segmean(const float* __restrict__ tok,
                                                 const int* __restrict__ wmap,
                                                 short* __restrict__ we_bf){
  int blk = blockIdx.x;
  int b = blk >> 9;          // / NW
  int w = blk & 511;
  const int* m = wmap + b * LL;
  int lo = 0, hi = LL;
  while (lo < hi){ int mid = (lo + hi) >> 1; if (m[mid] < w) lo = mid + 1; else hi = mid; }
  int s = lo;
  int lo2 = s, hi2 = LL;
  while (lo2 < hi2){ int mid = (lo2 + hi2) >> 1; if (m[mid] <= w) lo2 = mid + 1; else hi2 = mid; }
  int e = lo2;
  float cnt = (float)(e - s);
  float denom = fmaxf(cnt, 1.f);
  for (int j = threadIdx.x; j < HH; j += 256){
    float acc = 0.f;
    for (int r = s; r < e; ++r) acc += tok[((size_t)b * LL + r) * HH + j];
    we_bf[((size_t)b * NW + w) * HH + j] = f2bf(acc / denom);
  }
}

// ---------------- GEMM: C[M,N] = A[M,K](bf16) * W[N,K]^T(bf16) + b1[n] + b2[n] ----------------
__global__ __launch_bounds__(256) void k_gemm_bt(const short* __restrict__ Abf,
                                                 const short* __restrict__ Wbf,
                                                 const float* __restrict__ b1,
                                                 const float* __restrict__ b2,
                                                 float* __restrict__ Cf,
                                                 int M, int N, int K){
  __shared__ __attribute__((aligned(16))) short As[128 * 32];
  __shared__ __attribute__((aligned(16))) short Bs[128 * 32];
  int ntiles = N >> 7;
  int m0 = (blockIdx.x / ntiles) << 7;
  int n0 = (blockIdx.x % ntiles) << 7;
  int tid = threadIdx.x, lane = tid & 63, wv = tid >> 6;
  int wm = (wv >> 1) << 6, wn = (wv & 1) << 6;
  f32x4 acc[4][4] = {};
  for (int kk = 0; kk < K; kk += 32){
#pragma unroll
    for (int q = 0; q < 2; ++q){
      int e = q * 256 + tid;        // 16B granule: row = e/4, col = (e&3)*8 shorts
      int row = e >> 2, col = (e & 3) << 3;
      gload16(Abf + (size_t)(m0 + row) * K + kk + col, As + e * 8);
      gload16(Wbf + (size_t)(n0 + row) * K + kk + col, Bs + e * 8);
    }
    __syncthreads();
    short8 af[4], bfr[4];
#pragma unroll
    for (int x = 0; x < 4; ++x){
      af[x]  = *(const short8*)(As + (wm + x * 16 + (lane & 15)) * 32 + ((lane >> 4) << 3));
      bfr[x] = *(const short8*)(Bs + (wn + x * 16 + (lane & 15)) * 32 + ((lane >> 4) << 3));
    }
#pragma unroll
    for (int x = 0; x < 4; ++x)
#pragma unroll
      for (int y = 0; y < 4; ++y)
        acc[x][y] = __builtin_amdgcn_mfma_f32_16x16x32_bf16(af[x], bfr[y], acc[x][y], 0, 0, 0);
    __syncthreads();
  }
#pragma unroll
  for (int x = 0; x < 4; ++x)
#pragma unroll
    for (int y = 0; y < 4; ++y)
#pragma unroll
      for (int i = 0; i < 4; ++i){
        int mm = m0 + wm + x * 16 + ((lane >> 4) << 2) + i;
        int nn = n0 + wn + y * 16 + (lane & 15);
        Cf[(size_t)mm * N + nn] = acc[x][y][i] + b1[nn] + b2[nn];
      }
}

// ---------------- BiLSTM: tag-in-data + 2-chain batch rotation ----------------
// 12 WGs/dir x 512 threads. Batch split into halves X of 16 rows; ticks alternate
// halves. h cells stored as u32 = (bf16<<16) | (t+1). The tail of tick tt tag-checks
// and loads h for tick tt+1 — one full tick (~1600cy) after its store, so the MALL
// propagation (~900cy) is already done: first-try hit, no retry storm, no flags.
// Overwrite safety (per half X): storing h(X,t) requires validated h(X,t-1), which
// requires every WG stored h(X,t-1), which requires their loads of h(X,t-2) done —
// so buf slot (t&1) (holding tags t-1) is drained before tag-t+1 overwrite.
__global__ __launch_bounds__(512) void k_lstm(const float* __restrict__ xg_f,
                                              const float* __restrict__ xg_b,
                                              const short* __restrict__ whh_f,
                                              const short* __restrict__ whh_b,
                                              unsigned int* __restrict__ hbuf,
                                              short* __restrict__ hcat){
  int bx = blockIdx.x;
  int dir = bx / CWG;
  int cg  = bx % CWG;
  int tid = threadIdx.x, lane = tid & 63, wv = tid >> 6;
  int q = lane >> 4, fr = lane & 15;
  int g = wv >> 1, nh = wv & 1;                // gate, 16-col half of WG's 32 cols
  int jbase = g * HID + cg * WGC + nh * 16;
  const float* xg  = dir ? xg_b : xg_f;
  const short* whh = dir ? whh_b : whh_f;

  // resident Whh B-fragments: 16 gate-rows x K=384 -> 12 k-steps, 48 VGPRs
  short8 bfrag[12];
  {
    const short* wr = whh + (size_t)(jbase + fr) * HID + q * 8;
#pragma unroll
    for (int ks = 0; ks < 12; ++ks) bfrag[ks] = *(const short8*)(wr + ks * 32);
  }

  __shared__ __attribute__((aligned(16))) short hs[2][16 * HPAD];  // per-half staged h
  __shared__ float pre[4][16][34];                                 // gate preacts

  float cst0 = 0.f, cst1 = 0.f;              // cell state per half
  int eb = tid >> 5, ecol = tid & 31;        // elementwise cell + staging row (eb==sr)
  int sc = (tid & 31) * 12;                  // staging: 12 consecutive cells
  unsigned int* hbD = hbuf + (size_t)dir * 2 * 2 * 16 * HID;

  float xgv[4], nxg[4];
  {
    int t0a = dir ? (NW - 1) : 0;            // prologue xg for tick (X=0, t=0)
#pragma unroll
    for (int i = 0; i < 4; ++i)
      xgv[i] = xg[((size_t)(q * 4 + i) * NW + t0a) * G4 + jbase + fr];
  }
  u32x4 d0, d1, d2;                          // tagged h block (12 dwords), lives across ticks

  for (int tt = 0; tt < 2 * NW; ++tt){
    int X = tt & 1, t = tt >> 1;
    int t_act = dir ? (NW - 1 - t) : t;
    if (tt > 0){
#pragma unroll
      for (int i = 0; i < 4; ++i) xgv[i] = nxg[i];
    }
    if (t > 0){
      // strip tags (12 tagged u32 -> 6 packed u32 of 2 bf16) and stage to LDS
      unsigned int pk0 = (d0[0] >> 16) | (d0[1] & 0xffff0000u);
      unsigned int pk1 = (d0[2] >> 16) | (d0[3] & 0xffff0000u);
      unsigned int pk2 = (d1[0] >> 16) | (d1[1] & 0xffff0000u);
      unsigned int pk3 = (d1[2] >> 16) | (d1[3] & 0xffff0000u);
      unsigned int pk4 = (d2[0] >> 16) | (d2[1] & 0xffff0000u);
      unsigned int pk5 = (d2[2] >> 16) | (d2[3] & 0xffff0000u);
      short* dst = &hs[X][eb * HPAD + sc];
      u32x2 w0 = {pk0, pk1}, w1 = {pk2, pk3}, w2 = {pk4, pk5};
      *(u32x2*)(dst)     = w0;
      *(u32x2*)(dst + 4) = w1;
      *(u32x2*)(dst + 8) = w2;
      if (cg == 0){
        // one WG per dir mirrors h(X,t-1) to hcat (issue-only, off critical path)
        int tprev = dir ? (NW - t) : (t - 1);
        short* dh = hcat + ((size_t)(X * 16 + eb) * NW + tprev) * HH + dir * HID + sc;
        *(u32x2*)(dh)     = w0;
        *(u32x2*)(dh + 4) = w1;
        *(u32x2*)(dh + 8) = w2;
      }
    }
    asm volatile("s_waitcnt lgkmcnt(0)" ::: "memory");
    __builtin_amdgcn_s_barrier();            // barrier A: staging complete
    __builtin_amdgcn_sched_barrier(0);
    // MFMA for current tick (M=16 half-batch)
    f32x4 acc = {}, accB = {};
    if (t > 0){
      const short* hrow = &hs[X][fr * HPAD + q * 8];
#pragma unroll
      for (int ks = 0; ks < 6; ++ks)
        acc  = __builtin_amdgcn_mfma_f32_16x16x32_bf16(*(const short8*)(hrow + ks * 32), bfrag[ks], acc, 0, 0, 0);
#pragma unroll
      for (int ks = 6; ks < 12; ++ks)
        accB = __builtin_amdgcn_mfma_f32_16x16x32_bf16(*(const short8*)(hrow + ks * 32), bfrag[ks], accB, 0, 0, 0);
      acc += accB;
    }
#pragma unroll
    for (int i = 0; i < 4; ++i)
      pre[g][q * 4 + i][nh * 16 + fr] = acc[i] + xgv[i];
    asm volatile("s_waitcnt lgkmcnt(0)" ::: "memory");
    __builtin_amdgcn_s_barrier();            // barrier B: preacts ready
    __builtin_amdgcn_sched_barrier(0);
    // elementwise: 1 cell/thread (row eb of half X, col cg*32+ecol)
    float gi2 = pre[0][eb][ecol], gf2 = pre[1][eb][ecol];
    float gg2 = pre[2][eb][ecol], go2 = pre[3][eb][ecol];
    float c = X ? cst1 : cst0;
    c = sigm(gf2) * c + sigm(gi2) * ftanh(gg2);
    float h = sigm(go2) * ftanh(c);
    if (X) cst1 = c; else cst0 = c;
    unsigned int hv = (unsigned int)(unsigned short)f2bf(h);
    unsigned int wtag = (hv << 16) | ((unsigned int)(t + 1) & 0xffffu);
    unsigned int* hw = hbD + ((size_t)X * 2 + (t & 1)) * 16 * HID + eb * HID + cg * WGC + ecol;
    asm volatile("global_store_dword %0, %1, off sc0 sc1" :: "v"(hw), "v"(wtag) : "memory");
    if (t == NW - 1)   // final step per half: producers write hcat directly
      hcat[((size_t)(X * 16 + eb) * NW + t_act) * HH + dir * HID + cg * WGC + ecol] = (short)hv;
    // ---- tail: acquire data for tick tt+1 ----
    if (tt + 1 < 2 * NW){
      int Xn = (tt + 1) & 1, tn = (tt + 1) >> 1;
      int tna = dir ? (NW - 1 - tn) : tn;
#pragma unroll
      for (int i = 0; i < 4; ++i)
        nxg[i] = xg[((size_t)(Xn * 16 + q * 4 + i) * NW + tna) * G4 + jbase + fr];
      if (tn > 0){
        unsigned int expect = (unsigned int)tn & 0xffffu;
        const unsigned int* hp = hbD + ((size_t)Xn * 2 + ((tn - 1) & 1)) * 16 * HID + eb * HID + sc;
        for (;;){
          asm volatile("global_load_dwordx4 %0, %1, off sc0 sc1" : "=v"(d0) : "v"(hp + 0) : "memory");
          asm volatile("global_load_dwordx4 %0, %1, off sc0 sc1" : "=v"(d1) : "v"(hp + 4) : "memory");
          asm volatile("global_load_dwordx4 %0, %1, off sc0 sc1" : "=v"(d2) : "v"(hp + 8) : "memory");
          asm volatile("s_waitcnt vmcnt(0)" ::: "memory");
          __builtin_amdgcn_sched_barrier(0);
#define TAGBAD(dv) (((dv[0] ^ expect) | (dv[1] ^ expect) | (dv[2] ^ expect) | (dv[3] ^ expect)) & 0xffffu)
          unsigned int bad = TAGBAD(d0) | TAGBAD(d1) | TAGBAD(d2);
#undef TAGBAD
          if (__all(bad == 0)) break;
          __builtin_amdgcn_s_sleep(2);
        }
      }
    }
  }
}

// ---------------- gate MLP + softmax (per batch row) ----------------
__global__ __launch_bounds__(256) void k_gate(const float* __restrict__ tok,
                                              const int* __restrict__ lids,
                                              const float* __restrict__ ltab,
                                              const float* __restrict__ W1,
                                              const float* __restrict__ b1v,
                                              const float* __restrict__ W2,
                                              const float* __restrict__ b2v,
                                              float* __restrict__ gate){
  __shared__ float gin[GIN];
  __shared__ float hid[HH];
  __shared__ float pr[EE];
  int b = blockIdx.x, tid = threadIdx.x;
  int lid = lids[b];
  for (int i = tid; i < GIN; i += 256)
    gin[i] = (i < HH) ? tok[(size_t)b * LL * HH + i] : ltab[lid * DLL + (i - HH)];
  __syncthreads();
  for (int j = tid; j < HH; j += 256){
    float a = b1v[j];
    const float* wr = W1 + (size_t)j * GIN;
    for (int k = 0; k < GIN; ++k) a += gin[k] * wr[k];
    hid[j] = fmaxf(a, 0.f);
  }
  __syncthreads();
  int wv = tid >> 6, lane = tid & 63;
  if (wv < EE){
    float p = 0.f;
    for (int k = lane; k < HH; k += 64) p += hid[k] * W2[wv * HH + k];
#pragma unroll
    for (int off = 32; off; off >>= 1) p += __shfl_down(p, off);
    if (lane == 0) pr[wv] = p + b2v[wv];
  }
  __syncthreads();
  if (tid == 0){
    float mx = fmaxf(fmaxf(pr[0], pr[1]), fmaxf(pr[2], pr[3]));
    float s = 0.f, ex[EE];
    for (int e2 = 0; e2 < EE; ++e2){ ex[e2] = __expf(pr[e2] - mx); s += ex[e2]; }
    for (int e2 = 0; e2 < EE; ++e2) gate[b * EE + e2] = ex[e2] / s;
  }
}

// ---------------- head precompute: A = headW @ proj_W, c = headW.proj_b + head_b ----------------
__global__ __launch_bounds__(256) void k_headpre(const float* __restrict__ efW,
                                                 const float* __restrict__ efb,
                                                 const float* __restrict__ edW,
                                                 const float* __restrict__ edb,
                                                 const float* __restrict__ projW,
                                                 const float* __restrict__ projb,
                                                 float* __restrict__ Acomb,
                                                 float* __restrict__ Ccomb){
  int head = blockIdx.x >> 2, e2 = blockIdx.x & 3, tid = threadIdx.x;
  const float* Wv = head ? edW : efW;
  const float* bv = head ? edb : efb;
  __shared__ float wrow[HH];
  for (int i = tid; i < HH; i += 256) wrow[i] = Wv[e2 * HH + i];
  __syncthreads();
  for (int c = tid; c < HH; c += 256){
    float a = 0.f;
    for (int h2 = 0; h2 < HH; ++h2) a += wrow[h2] * projW[(size_t)h2 * HH + c];
    Acomb[(head * 4 + e2) * HH + c] = a;
  }
  int wv = tid >> 6, lane = tid & 63;
  if (wv == 0){
    float p = 0.f;
    for (int k = lane; k < HH; k += 64) p += wrow[k] * projb[k];
#pragma unroll
    for (int off = 32; off; off >>= 1) p += __shfl_down(p, off);
    if (lane == 0) Ccomb[head * 4 + e2] = p + bv[e2];
  }
}

// ---------------- fused expert heads: out = sum_e gate * (hcat.A_e + c_e) ----------------
__global__ __launch_bounds__(256) void k_heads(const short* __restrict__ hcat,
                                               const float* __restrict__ Acomb,
                                               const float* __restrict__ Ccomb,
                                               const float* __restrict__ gate,
                                               float* __restrict__ outp){
  __shared__ float Al[8 * HH];   // 24 KB
  int tid = threadIdx.x;
  for (int i = tid; i < 8 * HH; i += 256) Al[i] = Acomb[i];
  __syncthreads();
  int wv = tid >> 6, lane = tid & 63;
  int bw = blockIdx.x * 4 + wv;        // = b*512 + w
  const short* hr = hcat + (size_t)bw * HH;
  float hv[12];
#pragma unroll
  for (int j = 0; j < 12; ++j) hv[j] = bf2f(hr[lane + 64 * j]);
  float dsum[8];
#pragma unroll
  for (int v = 0; v < 8; ++v){
    float p = 0.f;
#pragma unroll
    for (int j = 0; j < 12; ++j) p += hv[j] * Al[v * HH + lane + 64 * j];
#pragma unroll
    for (int off = 32; off; off >>= 1) p += __shfl_xor(p, off);
    dsum[v] = p;
  }
  if (lane == 0){
    int b = bw >> 9;
    float fx = 0.f, du = 0.f;
#pragma unroll
    for (int e2 = 0; e2 < 4; ++e2){
      float g = gate[b * 4 + e2];
      fx += g * (dsum[e2]     + Ccomb[e2]);
      du += g * (dsum[4 + e2] + Ccomb[4 + e2]);
    }
    outp[bw] = fx;
    outp[BB * NW + bw] = du;
  }
}

extern "C" void kernel_launch(void* const* d_in, const int* in_sizes, int n_in,
                              void* d_out, int out_size, void* d_ws, size_t ws_size,
                              hipStream_t stream){
  const float* tok   = (const float*)d_in[0];
  const int*   wmap  = (const int*)d_in[1];
  const int*   lids  = (const int*)d_in[2];
  const float* Wih_f = (const float*)d_in[3];
  const float* Whh_f = (const float*)d_in[4];
  const float* bih_f = (const float*)d_in[5];
  const float* bhh_f = (const float*)d_in[6];
  const float* Wih_b = (const float*)d_in[7];
  const float* Whh_b = (const float*)d_in[8];
  const float* bih_b = (const float*)d_in[9];
  const float* bhh_b = (const float*)d_in[10];
  const float* projW = (const float*)d_in[11];
  const float* projb = (const float*)d_in[12];
  const float* ltab  = (const float*)d_in[13];
  const float* gW1   = (const float*)d_in[14];
  const float* gb1   = (const float*)d_in[15];
  const float* gW2   = (const float*)d_in[16];
  const float* gb2   = (const float*)d_in[17];
  const float* efW   = (const float*)d_in[18];
  const float* efb   = (const float*)d_in[19];
  const float* edW   = (const float*)d_in[20];
  const float* edb   = (const float*)d_in[21];
  float* outp = (float*)d_out;

  char* ws = (char*)d_ws;
  size_t off = 0;
  auto alloc = [&](size_t bytes) -> char* {
    char* p = ws + off;
    off = (off + bytes + 255) & ~(size_t)255;
    return p;
  };
  short* we_bf   = (short*)alloc((size_t)BB * NW * HH * 2);
  short* wihf_bf = (short*)alloc((size_t)G4 * HH * 2);
  short* wihb_bf = (short*)alloc((size_t)G4 * HH * 2);
  short* whhf_bf = (short*)alloc((size_t)G4 * HID * 2);
  short* whhb_bf = (short*)alloc((size_t)G4 * HID * 2);
  float* xg_f    = (float*)alloc((size_t)BB * NW * G4 * 4);
  float* xg_b    = (float*)alloc((size_t)BB * NW * G4 * 4);
  short* hcat    = (short*)alloc((size_t)BB * NW * HH * 2);
  unsigned int* hbuf = (unsigned int*)alloc((size_t)2 * 2 * 2 * 16 * HID * 4);  // tagged
  float* gateb   = (float*)alloc((size_t)BB * EE * 4);
  float* Acomb   = (float*)alloc((size_t)8 * HH * 4);
  float* Ccomb   = (float*)alloc((size_t)8 * 4);

  k_f2bf<<<1024, 256, 0, stream>>>(Wih_f, wihf_bf, G4 * HH);
  k_f2bf<<<1024, 256, 0, stream>>>(Wih_b, wihb_bf, G4 * HH);
  k_f2bf<<<512, 256, 0, stream>>>(Whh_f, whhf_bf, G4 * HID);
  k_f2bf<<<512, 256, 0, stream>>>(Whh_b, whhb_bf, G4 * HID);
  k_segmean<<<BB * NW, 256, 0, stream>>>(tok, wmap, we_bf);
  k_gemm_bt<<<(BB * NW / 128) * (G4 / 128), 256, 0, stream>>>(we_bf, wihf_bf, bih_f, bhh_f, xg_f, BB * NW, G4, HH);
  k_gemm_bt<<<(BB * NW / 128) * (G4 / 128), 256, 0, stream>>>(we_bf, wihb_bf, bih_b, bhh_b, xg_b, BB * NW, G4, HH);
  k_gate<<<BB, 256, 0, stream>>>(tok, lids, ltab, gW1, gb1, gW2, gb2, gateb);
  k_headpre<<<8, 256, 0, stream>>>(efW, efb, edW, edb, projW, projb, Acomb, Ccomb);
  k_lstm<<<2 * CWG, 512, 0, stream>>>(xg_f, xg_b, whhf_bf, whhb_bf, hbuf, hcat);
  k_heads<<<(BB * NW) / 4, 256, 0, stream>>>(hcat, Acomb, Ccomb, gateb, outp);
}

// Round 9
// 2378.108 us; speedup vs baseline: 1.3310x; 1.0848x over previous
//
#include <hip/hip_runtime.h>
#include <stdint.h>

#define BB 32
#define LL 1024
#define NW 512
#define HH 768
#define HID 384
#define G4 1536   // 4*HID
#define EE 4
#define DLL 128
#define GIN 896   // H+DL
#define CWG 12    // column-group WGs per direction
#define WGC 32    // h-cols per WG
#define HPAD 392  // padded LDS row stride (shorts)

typedef __attribute__((ext_vector_type(8))) short short8;
typedef __attribute__((ext_vector_type(4))) float f32x4;
typedef __attribute__((ext_vector_type(4))) unsigned int u32x4;
typedef __attribute__((ext_vector_type(2))) unsigned int u32x2;

__device__ __forceinline__ float bf2f(short s){
  union { unsigned int u; float f; } v; v.u = ((unsigned int)(unsigned short)s) << 16; return v.f;
}
__device__ __forceinline__ short f2bf(float f){
  union { float f; unsigned int u; } v; v.f = f;
  unsigned int r = v.u + 0x7fffu + ((v.u >> 16) & 1u);
  return (short)(r >> 16);
}
__device__ __forceinline__ float sigm(float x){ return 1.f / (1.f + __expf(-x)); }
__device__ __forceinline__ float ftanh(float x){ float e = __expf(2.f * x); return 1.f - 2.f / (e + 1.f); }

__device__ __forceinline__ void gload16(const void* g, void* l){
  __builtin_amdgcn_global_load_lds(
      (const __attribute__((address_space(1))) unsigned int*)g,
      (__attribute__((address_space(3))) unsigned int*)l, 16, 0, 0);
}

// ---------------- f32 -> bf16 convert ----------------
__global__ void k_f2bf(const float* in, short* out, int n){
  int i = blockIdx.x * blockDim.x + threadIdx.x;
  int st = gridDim.x * blockDim.x;
  for (; i < n; i += st) out[i] = f2bf(in[i]);
}

// ---------------- segment mean pooling ----------------
__global__ __launch_bounds__(256) void k_segmean(const float* __restrict__ tok,
                                                 const int* __restrict__ wmap,
                                                 short* __restrict__ we_bf){
  int blk = blockIdx.x;
  int b = blk >> 9;          // / NW
  int w = blk & 511;
  const int* m = wmap + b * LL;
  int lo = 0, hi = LL;
  while (lo < hi){ int mid = (lo + hi) >> 1; if (m[mid] < w) lo = mid + 1; else hi = mid; }
  int s = lo;
  int lo2 = s, hi2 = LL;
  while (lo2 < hi2){ int mid = (lo2 + hi2) >> 1; if (m[mid] <= w) lo2 = mid + 1; else hi2 = mid; }
  int e = lo2;
  float cnt = (float)(e - s);
  float denom = fmaxf(cnt, 1.f);
  for (int j = threadIdx.x; j < HH; j += 256){
    float acc = 0.f;
    for (int r = s; r < e; ++r) acc += tok[((size_t)b * LL + r) * HH + j];
    we_bf[((size_t)b * NW + w) * HH + j] = f2bf(acc / denom);
  }
}

// ---------------- GEMM: C[M,N] = A[M,K](bf16) * W[N,K]^T(bf16) + b1[n] + b2[n] ----------------
__global__ __launch_bounds__(256) void k_gemm_bt(const short* __restrict__ Abf,
                                                 const short* __restrict__ Wbf,
                                                 const float* __restrict__ b1,
                                                 const float* __restrict__ b2,
                                                 float* __restrict__ Cf,
                                                 int M, int N, int K){
  __shared__ __attribute__((aligned(16))) short As[128 * 32];
  __shared__ __attribute__((aligned(16))) short Bs[128 * 32];
  int ntiles = N >> 7;
  int m0 = (blockIdx.x / ntiles) << 7;
  int n0 = (blockIdx.x % ntiles) << 7;
  int tid = threadIdx.x, lane = tid & 63, wv = tid >> 6;
  int wm = (wv >> 1) << 6, wn = (wv & 1) << 6;
  f32x4 acc[4][4] = {};
  for (int kk = 0; kk < K; kk += 32){
#pragma unroll
    for (int q = 0; q < 2; ++q){
      int e = q * 256 + tid;        // 16B granule: row = e/4, col = (e&3)*8 shorts
      int row = e >> 2, col = (e & 3) << 3;
      gload16(Abf + (size_t)(m0 + row) * K + kk + col, As + e * 8);
      gload16(Wbf + (size_t)(n0 + row) * K + kk + col, Bs + e * 8);
    }
    __syncthreads();
    short8 af[4], bfr[4];
#pragma unroll
    for (int x = 0; x < 4; ++x){
      af[x]  = *(const short8*)(As + (wm + x * 16 + (lane & 15)) * 32 + ((lane >> 4) << 3));
      bfr[x] = *(const short8*)(Bs + (wn + x * 16 + (lane & 15)) * 32 + ((lane >> 4) << 3));
    }
#pragma unroll
    for (int x = 0; x < 4; ++x)
#pragma unroll
      for (int y = 0; y < 4; ++y)
        acc[x][y] = __builtin_amdgcn_mfma_f32_16x16x32_bf16(af[x], bfr[y], acc[x][y], 0, 0, 0);
    __syncthreads();
  }
#pragma unroll
  for (int x = 0; x < 4; ++x)
#pragma unroll
    for (int y = 0; y < 4; ++y)
#pragma unroll
      for (int i = 0; i < 4; ++i){
        int mm = m0 + wm + x * 16 + ((lane >> 4) << 2) + i;
        int nn = n0 + wn + y * 16 + (lane & 15);
        Cf[(size_t)mm * N + nn] = acc[x][y][i] + b1[nn] + b2[nn];
      }
}

// ---------------- BiLSTM: tag-in-data + 2-chain rotation + DEFERRED CHECK ----------------
// 12 WGs/dir x 512 threads. Ticks alternate batch halves X. h cells: u32 = (bf16<<16)|(t+1).
// Schedule: tick for (X,t) loads h(X',t') for the NEXT tick mid-tick (producer store is
// ~1000cy old -> propagated) and CHECKS it at the head of the next tick (load had ~500cy
// flight). Neither MALL propagation nor load RT ever blocks; retries only on real misses.
// Overwrite safety: storing h(X,t) requires validated h(X,t-1) (head of this tick), which
// required every WG's store of h(X,t-1), which required their validation of h(X,t-2) —
// so the slot being overwritten (parity t&1, holding tags t-1) is globally consumed.
// Replay-safe: poison tag 0xAAAA never matches; stale tags from a previous replay match
// only for the same step, whose values are bitwise identical (deterministic recurrence).
__global__ __launch_bounds__(512) void k_lstm(const float* __restrict__ xg_f,
                                              const float* __restrict__ xg_b,
                                              const short* __restrict__ whh_f,
                                              const short* __restrict__ whh_b,
                                              unsigned int* __restrict__ hbuf,
                                              short* __restrict__ hcat){
  int bx = blockIdx.x;
  int dir = bx / CWG;
  int cg  = bx % CWG;
  int tid = threadIdx.x, lane = tid & 63, wv = tid >> 6;
  int q = lane >> 4, fr = lane & 15;
  int g = wv >> 1, nh = wv & 1;                // gate, 16-col half of WG's 32 cols
  int jbase = g * HID + cg * WGC + nh * 16;
  const float* xg  = dir ? xg_b : xg_f;
  const short* whh = dir ? whh_b : whh_f;

  // resident Whh B-fragments: 16 gate-rows x K=384 -> 12 k-steps, 48 VGPRs
  short8 bfrag[12];
  {
    const short* wr = whh + (size_t)(jbase + fr) * HID + q * 8;
#pragma unroll
    for (int ks = 0; ks < 12; ++ks) bfrag[ks] = *(const short8*)(wr + ks * 32);
  }

  __shared__ __attribute__((aligned(16))) short hs[2][16 * HPAD];  // per-half staged h
  __shared__ float pre[4][16][34];                                 // gate preacts

  float cst0 = 0.f, cst1 = 0.f;              // cell state per half
  int eb = tid >> 5, ecol = tid & 31;        // elementwise cell row/col; staging row eb
  int sc = (tid & 31) * 12;                  // staging: 12 consecutive cells
  unsigned int* hbD = hbuf + (size_t)dir * 2 * 2 * 16 * HID;

  float nxg[4];
  {
    int t0a = dir ? (NW - 1) : 0;            // prologue xg for tick (X=0, t=0)
    const float* xp = xg + (size_t)t0a * G4 + jbase + fr;
#pragma unroll
    for (int i = 0; i < 4; ++i)
      nxg[i] = xp[(size_t)(q * 4 + i) * NW * G4];
  }
  u32x4 d0, d1, d2;                          // tagged h block (12 dwords), in flight across ticks
  const unsigned int* hp_sav = hbD;          // retry pointer

  for (int tt = 0; tt < 2 * NW; ++tt){
    int X = tt & 1, t = tt >> 1;
    int t_act = dir ? (NW - 1 - t) : t;
    // ---- head: drain everything in flight (h-load, xg, prior stores) ----
    asm volatile("s_waitcnt vmcnt(0)" ::: "memory");
    __builtin_amdgcn_sched_barrier(0);
    if (t > 0){
      // deferred tag check (load has been in flight since mid previous tick)
      unsigned int expect = (unsigned int)t & 0xffffu;
      for (;;){
#define TAGBAD(dv) (((dv[0] ^ expect) | (dv[1] ^ expect) | (dv[2] ^ expect) | (dv[3] ^ expect)) & 0xffffu)
        unsigned int bad = TAGBAD(d0) | TAGBAD(d1) | TAGBAD(d2);
#undef TAGBAD
        if (__all(bad == 0)) break;
        __builtin_amdgcn_s_sleep(1);
        asm volatile("global_load_dwordx4 %0, %1, off sc0 sc1" : "=v"(d0) : "v"(hp_sav + 0) : "memory");
        asm volatile("global_load_dwordx4 %0, %1, off sc0 sc1" : "=v"(d1) : "v"(hp_sav + 4) : "memory");
        asm volatile("global_load_dwordx4 %0, %1, off sc0 sc1" : "=v"(d2) : "v"(hp_sav + 8) : "memory");
        asm volatile("s_waitcnt vmcnt(0)" ::: "memory");
        __builtin_amdgcn_sched_barrier(0);
      }
      // strip tags (12 tagged u32 -> 6 packed u32 of 2 bf16) and stage to LDS
      unsigned int pk0 = (d0[0] >> 16) | (d0[1] & 0xffff0000u);
      unsigned int pk1 = (d0[2] >> 16) | (d0[3] & 0xffff0000u);
      unsigned int pk2 = (d1[0] >> 16) | (d1[1] & 0xffff0000u);
      unsigned int pk3 = (d1[2] >> 16) | (d1[3] & 0xffff0000u);
      unsigned int pk4 = (d2[0] >> 16) | (d2[1] & 0xffff0000u);
      unsigned int pk5 = (d2[2] >> 16) | (d2[3] & 0xffff0000u);
      short* dst = &hs[X][eb * HPAD + sc];
      u32x2 w0 = {pk0, pk1}, w1 = {pk2, pk3}, w2 = {pk4, pk5};
      *(u32x2*)(dst)     = w0;
      *(u32x2*)(dst + 4) = w1;
      *(u32x2*)(dst + 8) = w2;
      if (cg == 0){
        // one WG per dir mirrors h(X,t-1) to hcat (issue-only, off critical path)
        int tprev = dir ? (NW - t) : (t - 1);
        short* dh = hcat + ((size_t)(X * 16 + eb) * NW + tprev) * HH + dir * HID + sc;
        *(u32x2*)(dh)     = w0;
        *(u32x2*)(dh + 4) = w1;
        *(u32x2*)(dh + 8) = w2;
      }
    }
    asm volatile("s_waitcnt lgkmcnt(0)" ::: "memory");
    __builtin_amdgcn_s_barrier();            // barrier A: staging complete
    __builtin_amdgcn_sched_barrier(0);
    // ---- MFMA for current tick (M=16 half-batch) ----
    f32x4 acc = {}, accB = {};
    if (t > 0){
      const short* hrow = &hs[X][fr * HPAD + q * 8];
#pragma unroll
      for (int ks = 0; ks < 6; ++ks)
        acc  = __builtin_amdgcn_mfma_f32_16x16x32_bf16(*(const short8*)(hrow + ks * 32), bfrag[ks], acc, 0, 0, 0);
#pragma unroll
      for (int ks = 6; ks < 12; ++ks)
        accB = __builtin_amdgcn_mfma_f32_16x16x32_bf16(*(const short8*)(hrow + ks * 32), bfrag[ks], accB, 0, 0, 0);
      acc += accB;
    }
#pragma unroll
    for (int i = 0; i < 4; ++i)
      pre[g][q * 4 + i][nh * 16 + fr] = acc[i] + nxg[i];
    __builtin_amdgcn_sched_barrier(0);
    // ---- mid-tick: issue next tick's loads (producer store is ~1000cy old) ----
    if (tt + 1 < 2 * NW){
      int Xn = 1 - X, tn = X ? (t + 1) : t;
      int tna = dir ? (NW - 1 - tn) : tn;
      const float* xp = xg + ((size_t)(Xn * 16) * NW + tna) * G4 + jbase + fr;
#pragma unroll
      for (int i = 0; i < 4; ++i)
        nxg[i] = xp[(size_t)(q * 4 + i) * NW * G4];
      if (tn > 0){
        hp_sav = hbD + ((size_t)Xn * 2 + ((tn - 1) & 1)) * 16 * HID + eb * HID + sc;
        asm volatile("global_load_dwordx4 %0, %1, off sc0 sc1" : "=v"(d0) : "v"(hp_sav + 0) : "memory");
        asm volatile("global_load_dwordx4 %0, %1, off sc0 sc1" : "=v"(d1) : "v"(hp_sav + 4) : "memory");
        asm volatile("global_load_dwordx4 %0, %1, off sc0 sc1" : "=v"(d2) : "v"(hp_sav + 8) : "memory");
      }
    }
    asm volatile("s_waitcnt lgkmcnt(0)" ::: "memory");
    __builtin_amdgcn_s_barrier();            // barrier B: preacts ready
    __builtin_amdgcn_sched_barrier(0);
    // ---- elementwise: 1 cell/thread (row eb of half X, col cg*32+ecol) ----
    float gi2 = pre[0][eb][ecol], gf2 = pre[1][eb][ecol];
    float gg2 = pre[2][eb][ecol], go2 = pre[3][eb][ecol];
    float c = X ? cst1 : cst0;
    c = sigm(gf2) * c + sigm(gi2) * ftanh(gg2);
    float h = sigm(go2) * ftanh(c);
    if (X) cst1 = c; else cst0 = c;
    unsigned int hv = (unsigned int)(unsigned short)f2bf(h);
    unsigned int wtag = (hv << 16) | ((unsigned int)(t + 1) & 0xffffu);
    unsigned int* hw = hbD + ((size_t)X * 2 + (t & 1)) * 16 * HID + eb * HID + cg * WGC + ecol;
    asm volatile("global_store_dword %0, %1, off sc0 sc1" :: "v"(hw), "v"(wtag) : "memory");
    if (t == NW - 1)   // final step per half: producers write hcat directly
      hcat[((size_t)(X * 16 + eb) * NW + t_act) * HH + dir * HID + cg * WGC + ecol] = (short)hv;
    // store drains at next head's vmcnt(0); its visibility is covered by one full tick
  }
}

// ---------------- gate MLP + softmax (per batch row) ----------------
__global__ __launch_bounds__(256) void k_gate(const float* __restrict__ tok,
                                              const int* __restrict__ lids,
                                              const float* __restrict__ ltab,
                                              const float* __restrict__ W1,
                                              const float* __restrict__ b1v,
                                              const float* __restrict__ W2,
                                              const float* __restrict__ b2v,
                                              float* __restrict__ gate){
  __shared__ float gin[GIN];
  __shared__ float hid[HH];
  __shared__ float pr[EE];
  int b = blockIdx.x, tid = threadIdx.x;
  int lid = lids[b];
  for (int i = tid; i < GIN; i += 256)
    gin[i] = (i < HH) ? tok[(size_t)b * LL * HH + i] : ltab[lid * DLL + (i - HH)];
  __syncthreads();
  for (int j = tid; j < HH; j += 256){
    float a = b1v[j];
    const float* wr = W1 + (size_t)j * GIN;
    for (int k = 0; k < GIN; ++k) a += gin[k] * wr[k];
    hid[j] = fmaxf(a, 0.f);
  }
  __syncthreads();
  int wv = tid >> 6, lane = tid & 63;
  if (wv < EE){
    float p = 0.f;
    for (int k = lane; k < HH; k += 64) p += hid[k] * W2[wv * HH + k];
#pragma unroll
    for (int off = 32; off; off >>= 1) p += __shfl_down(p, off);
    if (lane == 0) pr[wv] = p + b2v[wv];
  }
  __syncthreads();
  if (tid == 0){
    float mx = fmaxf(fmaxf(pr[0], pr[1]), fmaxf(pr[2], pr[3]));
    float s = 0.f, ex[EE];
    for (int e2 = 0; e2 < EE; ++e2){ ex[e2] = __expf(pr[e2] - mx); s += ex[e2]; }
    for (int e2 = 0; e2 < EE; ++e2) gate[b * EE + e2] = ex[e2] / s;
  }
}

// ---------------- head precompute: A = headW @ proj_W, c = headW.proj_b + head_b ----------------
__global__ __launch_bounds__(256) void k_headpre(const float* __restrict__ efW,
                                                 const float* __restrict__ efb,
                                                 const float* __restrict__ edW,
                                                 const float* __restrict__ edb,
                                                 const float* __restrict__ projW,
                                                 const float* __restrict__ projb,
                                                 float* __restrict__ Acomb,
                                                 float* __restrict__ Ccomb){
  int head = blockIdx.x >> 2, e2 = blockIdx.x & 3, tid = threadIdx.x;
  const float* Wv = head ? edW : efW;
  const float* bv = head ? edb : efb;
  __shared__ float wrow[HH];
  for (int i = tid; i < HH; i += 256) wrow[i] = Wv[e2 * HH + i];
  __syncthreads();
  for (int c = tid; c < HH; c += 256){
    float a = 0.f;
    for (int h2 = 0; h2 < HH; ++h2) a += wrow[h2] * projW[(size_t)h2 * HH + c];
    Acomb[(head * 4 + e2) * HH + c] = a;
  }
  int wv = tid >> 6, lane = tid & 63;
  if (wv == 0){
    float p = 0.f;
    for (int k = lane; k < HH; k += 64) p += wrow[k] * projb[k];
#pragma unroll
    for (int off = 32; off; off >>= 1) p += __shfl_down(p, off);
    if (lane == 0) Ccomb[head * 4 + e2] = p + bv[e2];
  }
}

// ---------------- fused expert heads: out = sum_e gate * (hcat.A_e + c_e) ----------------
__global__ __launch_bounds__(256) void k_heads(const short* __restrict__ hcat,
                                               const float* __restrict__ Acomb,
                                               const float* __restrict__ Ccomb,
                                               const float* __restrict__ gate,
                                               float* __restrict__ outp){
  __shared__ float Al[8 * HH];   // 24 KB
  int tid = threadIdx.x;
  for (int i = tid; i < 8 * HH; i += 256) Al[i] = Acomb[i];
  __syncthreads();
  int wv = tid >> 6, lane = tid & 63;
  int bw = blockIdx.x * 4 + wv;        // = b*512 + w
  const short* hr = hcat + (size_t)bw * HH;
  float hv[12];
#pragma unroll
  for (int j = 0; j < 12; ++j) hv[j] = bf2f(hr[lane + 64 * j]);
  float dsum[8];
#pragma unroll
  for (int v = 0; v < 8; ++v){
    float p = 0.f;
#pragma unroll
    for (int j = 0; j < 12; ++j) p += hv[j] * Al[v * HH + lane + 64 * j];
#pragma unroll
    for (int off = 32; off; off >>= 1) p += __shfl_xor(p, off);
    dsum[v] = p;
  }
  if (lane == 0){
    int b = bw >> 9;
    float fx = 0.f, du = 0.f;
#pragma unroll
    for (int e2 = 0; e2 < 4; ++e2){
      float g = gate[b * 4 + e2];
      fx += g * (dsum[e2]     + Ccomb[e2]);
      du += g * (dsum[4 + e2] + Ccomb[4 + e2]);
    }
    outp[bw] = fx;
    outp[BB * NW + bw] = du;
  }
}

extern "C" void kernel_launch(void* const* d_in, const int* in_sizes, int n_in,
                              void* d_out, int out_size, void* d_ws, size_t ws_size,
                              hipStream_t stream){
  const float* tok   = (const float*)d_in[0];
  const int*   wmap  = (const int*)d_in[1];
  const int*   lids  = (const int*)d_in[2];
  const float* Wih_f = (const float*)d_in[3];
  const float* Whh_f = (const float*)d_in[4];
  const float* bih_f = (const float*)d_in[5];
  const float* bhh_f = (const float*)d_in[6];
  const float* Wih_b = (const float*)d_in[7];
  const float* Whh_b = (const float*)d_in[8];
  const float* bih_b = (const float*)d_in[9];
  const float* bhh_b = (const float*)d_in[10];
  const float* projW = (const float*)d_in[11];
  const float* projb = (const float*)d_in[12];
  const float* ltab  = (const float*)d_in[13];
  const float* gW1   = (const float*)d_in[14];
  const float* gb1   = (const float*)d_in[15];
  const float* gW2   = (const float*)d_in[16];
  const float* gb2   = (const float*)d_in[17];
  const float* efW   = (const float*)d_in[18];
  const float* efb   = (const float*)d_in[19];
  const float* edW   = (const float*)d_in[20];
  const float* edb   = (const float*)d_in[21];
  float* outp = (float*)d_out;

  char* ws = (char*)d_ws;
  size_t off = 0;
  auto alloc = [&](size_t bytes) -> char* {
    char* p = ws + off;
    off = (off + bytes + 255) & ~(size_t)255;
    return p;
  };
  short* we_bf   = (short*)alloc((size_t)BB * NW * HH * 2);
  short* wihf_bf = (short*)alloc((size_t)G4 * HH * 2);
  short* wihb_bf = (short*)alloc((size_t)G4 * HH * 2);
  short* whhf_bf = (short*)alloc((size_t)G4 * HID * 2);
  short* whhb_bf = (short*)alloc((size_t)G4 * HID * 2);
  float* xg_f    = (float*)alloc((size_t)BB * NW * G4 * 4);
  float* xg_b    = (float*)alloc((size_t)BB * NW * G4 * 4);
  short* hcat    = (short*)alloc((size_t)BB * NW * HH * 2);
  unsigned int* hbuf = (unsigned int*)alloc((size_t)2 * 2 * 2 * 16 * HID * 4);  // tagged
  float* gateb   = (float*)alloc((size_t)BB * EE * 4);
  float* Acomb   = (float*)alloc((size_t)8 * HH * 4);
  float* Ccomb   = (float*)alloc((size_t)8 * 4);

  k_f2bf<<<1024, 256, 0, stream>>>(Wih_f, wihf_bf, G4 * HH);
  k_f2bf<<<1024, 256, 0, stream>>>(Wih_b, wihb_bf, G4 * HH);
  k_f2bf<<<512, 256, 0, stream>>>(Whh_f, whhf_bf, G4 * HID);
  k_f2bf<<<512, 256, 0, stream>>>(Whh_b, whhb_bf, G4 * HID);
  k_segmean<<<BB * NW, 256, 0, stream>>>(tok, wmap, we_bf);
  k_gemm_bt<<<(BB * NW / 128) * (G4 / 128), 256, 0, stream>>>(we_bf, wihf_bf, bih_f, bhh_f, xg_f, BB * NW, G4, HH);
  k_gemm_bt<<<(BB * NW / 128) * (G4 / 128), 256, 0, stream>>>(we_bf, wihb_bf, bih_b, bhh_b, xg_b, BB * NW, G4, HH);
  k_gate<<<BB, 256, 0, stream>>>(tok, lids, ltab, gW1, gb1, gW2, gb2, gateb);
  k_headpre<<<8, 256, 0, stream>>>(efW, efb, edW, edb, projW, projb, Acomb, Ccomb);
  k_lstm<<<2 * CWG, 512, 0, stream>>>(xg_f, xg_b, whhf_bf, whhb_bf, hbuf, hcat);
  k_heads<<<(BB * NW) / 4, 256, 0, stream>>>(hcat, Acomb, Ccomb, gateb, outp);
}

// Round 10
// 2074.797 us; speedup vs baseline: 1.5256x; 1.1462x over previous
//
#include <hip/hip_runtime.h>
#include <stdint.h>

#define BB 32
#define LL 1024
#define NW 512
#define HH 768
#define HID 384
#define G4 1536   // 4*HID
#define EE 4
#define DLL 128
#define GIN 896   // H+DL
#define CWG 12    // column-group WGs per direction
#define WGC 32    // h-cols per WG
#define HPAD 392  // padded LDS row stride (shorts)

typedef __attribute__((ext_vector_type(8))) short short8;
typedef __attribute__((ext_vector_type(4))) float f32x4;
typedef __attribute__((ext_vector_type(4))) unsigned int u32x4;
typedef __attribute__((ext_vector_type(2))) unsigned int u32x2;

__device__ __forceinline__ float bf2f(short s){
  union { unsigned int u; float f; } v; v.u = ((unsigned int)(unsigned short)s) << 16; return v.f;
}
__device__ __forceinline__ short f2bf(float f){
  union { float f; unsigned int u; } v; v.f = f;
  unsigned int r = v.u + 0x7fffu + ((v.u >> 16) & 1u);
  return (short)(r >> 16);
}
__device__ __forceinline__ float sigm(float x){ return 1.f / (1.f + __expf(-x)); }
__device__ __forceinline__ float ftanh(float x){ float e = __expf(2.f * x); return 1.f - 2.f / (e + 1.f); }

__device__ __forceinline__ void gload16(const void* g, void* l){
  __builtin_amdgcn_global_load_lds(
      (const __attribute__((address_space(1))) unsigned int*)g,
      (__attribute__((address_space(3))) unsigned int*)l, 16, 0, 0);
}

// ---------------- f32 -> bf16 convert ----------------
__global__ void k_f2bf(const float* in, short* out, int n){
  int i = blockIdx.x * blockDim.x + threadIdx.x;
  int st = gridDim.x * blockDim.x;
  for (; i < n; i += st) out[i] = f2bf(in[i]);
}

// ---------------- segment mean pooling ----------------
__global__ __launch_bounds__(256) void k_segmean(const float* __restrict__ tok,
                                                 const int* __restrict__ wmap,
                                                 short* __restrict__ we_bf){
  int blk = blockIdx.x;
  int b = blk >> 9;          // / NW
  int w = blk & 511;
  const int* m = wmap + b * LL;
  int lo = 0, hi = LL;
  while (lo < hi){ int mid = (lo + hi) >> 1; if (m[mid] < w) lo = mid + 1; else hi = mid; }
  int s = lo;
  int lo2 = s, hi2 = LL;
  while (lo2 < hi2){ int mid = (lo2 + hi2) >> 1; if (m[mid] <= w) lo2 = mid + 1; else hi2 = mid; }
  int e = lo2;
  float cnt = (float)(e - s);
  float denom = fmaxf(cnt, 1.f);
  for (int j = threadIdx.x; j < HH; j += 256){
    float acc = 0.f;
    for (int r = s; r < e; ++r) acc += tok[((size_t)b * LL + r) * HH + j];
    we_bf[((size_t)b * NW + w) * HH + j] = f2bf(acc / denom);
  }
}

// ---------------- GEMM: C[M,N] = A[M,K](bf16) * W[N,K]^T(bf16) + b1[n] + b2[n] ----------------
__global__ __launch_bounds__(256) void k_gemm_bt(const short* __restrict__ Abf,
                                                 const short* __restrict__ Wbf,
                                                 const float* __restrict__ b1,
                                                 const float* __restrict__ b2,
                                                 float* __restrict__ Cf,
                                                 int M, int N, int K){
  __shared__ __attribute__((aligned(16))) short As[128 * 32];
  __shared__ __attribute__((aligned(16))) short Bs[128 * 32];
  int ntiles = N >> 7;
  int m0 = (blockIdx.x / ntiles) << 7;
  int n0 = (blockIdx.x % ntiles) << 7;
  int tid = threadIdx.x, lane = tid & 63, wv = tid >> 6;
  int wm = (wv >> 1) << 6, wn = (wv & 1) << 6;
  f32x4 acc[4][4] = {};
  for (int kk = 0; kk < K; kk += 32){
#pragma unroll
    for (int q = 0; q < 2; ++q){
      int e = q * 256 + tid;        // 16B granule: row = e/4, col = (e&3)*8 shorts
      int row = e >> 2, col = (e & 3) << 3;
      gload16(Abf + (size_t)(m0 + row) * K + kk + col, As + e * 8);
      gload16(Wbf + (size_t)(n0 + row) * K + kk + col, Bs + e * 8);
    }
    __syncthreads();
    short8 af[4], bfr[4];
#pragma unroll
    for (int x = 0; x < 4; ++x){
      af[x]  = *(const short8*)(As + (wm + x * 16 + (lane & 15)) * 32 + ((lane >> 4) << 3));
      bfr[x] = *(const short8*)(Bs + (wn + x * 16 + (lane & 15)) * 32 + ((lane >> 4) << 3));
    }
#pragma unroll
    for (int x = 0; x < 4; ++x)
#pragma unroll
      for (int y = 0; y < 4; ++y)
        acc[x][y] = __builtin_amdgcn_mfma_f32_16x16x32_bf16(af[x], bfr[y], acc[x][y], 0, 0, 0);
    __syncthreads();
  }
#pragma unroll
  for (int x = 0; x < 4; ++x)
#pragma unroll
    for (int y = 0; y < 4; ++y)
#pragma unroll
      for (int i = 0; i < 4; ++i){
        int mm = m0 + wm + x * 16 + ((lane >> 4) << 2) + i;
        int nn = n0 + wn + y * 16 + (lane & 15);
        Cf[(size_t)mm * N + nn] = acc[x][y][i] + b1[nn] + b2[nn];
      }
}

#define TAGBAD(dv) (((dv[0] ^ expect) | (dv[1] ^ expect) | (dv[2] ^ expect) | (dv[3] ^ expect)) & 0xffffu)

// ---------------- BiLSTM: tags + 2-chain rotation + COUNTED vmcnt (no vmcnt(0)) ----------------
// All loop vmem is inline asm so the compiler emits no waitcnts of its own. Issue order per
// tick: [mirror(st3,cg0)] .. mid: h-load(3) then xg(4) .. end: store(1). In-order vmcnt
// retirement => head wait vmcnt(5) retires this tick's h-load AND its xg (older), while the
// next tick's xg(4)+store(1) stay in flight. xg prefetch depth = 2 ticks (covers HBM latency).
__global__ __launch_bounds__(512) void k_lstm(const float* __restrict__ xg_f,
                                              const float* __restrict__ xg_b,
                                              const short* __restrict__ whh_f,
                                              const short* __restrict__ whh_b,
                                              unsigned int* __restrict__ hbuf,
                                              short* __restrict__ hcat){
  int bx = blockIdx.x;
  int dir = bx / CWG;
  int cg  = bx % CWG;
  int tid = threadIdx.x, lane = tid & 63, wv = tid >> 6;
  int q = lane >> 4, fr = lane & 15;
  int g = wv >> 1, nh = wv & 1;                // gate, 16-col half of WG's 32 cols
  int jbase = g * HID + cg * WGC + nh * 16;
  const float* xg  = dir ? xg_b : xg_f;
  const short* whh = dir ? whh_b : whh_f;

  // resident Whh B-fragments via asm (keeps compiler vmem out of the kernel entirely)
  short8 bfrag[12];
  {
    const short* wr = whh + (size_t)(jbase + fr) * HID + q * 8;
#pragma unroll
    for (int ks = 0; ks < 12; ++ks)
      asm volatile("global_load_dwordx4 %0, %1, off" : "=v"(bfrag[ks]) : "v"(wr + ks * 32) : "memory");
    asm volatile("s_waitcnt vmcnt(0)" ::: "memory");
    __builtin_amdgcn_sched_barrier(0);
  }

  __shared__ __attribute__((aligned(16))) short hs[2][16 * HPAD];
  __shared__ float pre[4][16][34];

  float cA = 0.f, cB = 0.f;
  int eb = tid >> 5, ecol = tid & 31;
  int sc = (tid & 31) * 12;                    // staging: 12 consecutive u32 cells
  unsigned int* hbD = hbuf + (size_t)dir * 2 * 2 * 16 * HID;
  const size_t RS = (size_t)NW * G4;

  float xa0, xa1, xa2, xa3, xb0, xb1, xb2, xb3;
  u32x4 dA0, dA1, dA2, dB0, dB1, dB2;

  // prologue: xg(tick0: X0,t0) then xg(tick1: X1,t0)
  {
    int ta = dir ? (NW - 1) : 0;
    const float* xpA = xg + (size_t)ta * G4 + jbase + fr;
    asm volatile("global_load_dword %0, %1, off" : "=v"(xa0) : "v"(xpA + (size_t)(q*4+0)*RS) : "memory");
    asm volatile("global_load_dword %0, %1, off" : "=v"(xa1) : "v"(xpA + (size_t)(q*4+1)*RS) : "memory");
    asm volatile("global_load_dword %0, %1, off" : "=v"(xa2) : "v"(xpA + (size_t)(q*4+2)*RS) : "memory");
    asm volatile("global_load_dword %0, %1, off" : "=v"(xa3) : "v"(xpA + (size_t)(q*4+3)*RS) : "memory");
    const float* xpB = xpA + (size_t)16 * RS;
    asm volatile("global_load_dword %0, %1, off" : "=v"(xb0) : "v"(xpB + (size_t)(q*4+0)*RS) : "memory");
    asm volatile("global_load_dword %0, %1, off" : "=v"(xb1) : "v"(xpB + (size_t)(q*4+1)*RS) : "memory");
    asm volatile("global_load_dword %0, %1, off" : "=v"(xb2) : "v"(xpB + (size_t)(q*4+2)*RS) : "memory");
    asm volatile("global_load_dword %0, %1, off" : "=v"(xb3) : "v"(xpB + (size_t)(q*4+3)*RS) : "memory");
  }

  for (int j = 0; j < NW; ++j){
    int t_act = dir ? (NW - 1 - j) : j;
    //================ tick A: X=0, t=j ================
    if (j == 0) { asm volatile("s_waitcnt vmcnt(4)" ::: "memory"); }
    else        { asm volatile("s_waitcnt vmcnt(5)" ::: "memory"); }
    __builtin_amdgcn_sched_barrier(0);
    if (j > 0){
      unsigned int expect = (unsigned int)j & 0xffffu;
      const unsigned int* hpr = hbD + (size_t)((j - 1) & 1) * 16 * HID + eb * HID + sc;  // X=0 slots
      for (;;){
        unsigned int bad = TAGBAD(dA0) | TAGBAD(dA1) | TAGBAD(dA2);
        if (__all(bad == 0)) break;
        __builtin_amdgcn_s_sleep(1);
        asm volatile("global_load_dwordx4 %0, %1, off sc0 sc1" : "=v"(dA0) : "v"(hpr + 0) : "memory");
        asm volatile("global_load_dwordx4 %0, %1, off sc0 sc1" : "=v"(dA1) : "v"(hpr + 4) : "memory");
        asm volatile("global_load_dwordx4 %0, %1, off sc0 sc1" : "=v"(dA2) : "v"(hpr + 8) : "memory");
        asm volatile("s_waitcnt vmcnt(0)" ::: "memory");
        __builtin_amdgcn_sched_barrier(0);
      }
      unsigned int pk0 = (dA0[0] >> 16) | (dA0[1] & 0xffff0000u);
      unsigned int pk1 = (dA0[2] >> 16) | (dA0[3] & 0xffff0000u);
      unsigned int pk2 = (dA1[0] >> 16) | (dA1[1] & 0xffff0000u);
      unsigned int pk3 = (dA1[2] >> 16) | (dA1[3] & 0xffff0000u);
      unsigned int pk4 = (dA2[0] >> 16) | (dA2[1] & 0xffff0000u);
      unsigned int pk5 = (dA2[2] >> 16) | (dA2[3] & 0xffff0000u);
      u32x2 w0 = {pk0, pk1}, w1 = {pk2, pk3}, w2 = {pk4, pk5};
      short* dst = &hs[0][eb * HPAD + sc];
      *(u32x2*)(dst)     = w0;
      *(u32x2*)(dst + 4) = w1;
      *(u32x2*)(dst + 8) = w2;
      if (cg == 0){
        int tprev = dir ? (NW - j) : (j - 1);
        short* dh = hcat + ((size_t)eb * NW + tprev) * HH + dir * HID + sc;
        asm volatile("global_store_dwordx2 %0, %1, off" :: "v"(dh),     "v"(w0) : "memory");
        asm volatile("global_store_dwordx2 %0, %1, off" :: "v"(dh + 4), "v"(w1) : "memory");
        asm volatile("global_store_dwordx2 %0, %1, off" :: "v"(dh + 8), "v"(w2) : "memory");
      }
    }
    asm volatile("s_waitcnt lgkmcnt(0)" ::: "memory");
    __builtin_amdgcn_s_barrier();
    __builtin_amdgcn_sched_barrier(0);
    f32x4 acc = {}, acc2 = {};
    if (j > 0){
      const short* hrow = &hs[0][fr * HPAD + q * 8];
#pragma unroll
      for (int ks = 0; ks < 6; ++ks)
        acc  = __builtin_amdgcn_mfma_f32_16x16x32_bf16(*(const short8*)(hrow + ks * 32), bfrag[ks], acc, 0, 0, 0);
#pragma unroll
      for (int ks = 6; ks < 12; ++ks)
        acc2 = __builtin_amdgcn_mfma_f32_16x16x32_bf16(*(const short8*)(hrow + ks * 32), bfrag[ks], acc2, 0, 0, 0);
      acc += acc2;
    }
    pre[g][q*4+0][nh*16+fr] = acc[0] + xa0;
    pre[g][q*4+1][nh*16+fr] = acc[1] + xa1;
    pre[g][q*4+2][nh*16+fr] = acc[2] + xa2;
    pre[g][q*4+3][nh*16+fr] = acc[3] + xa3;
    // mid: h-load for tick B (h(X1,j-1)) FIRST, then xg for next tick A (X0,j+1)
    if (j > 0){
      const unsigned int* hpn = hbD + ((size_t)2 + ((j - 1) & 1)) * 16 * HID + eb * HID + sc;  // X=1 slots
      asm volatile("global_load_dwordx4 %0, %1, off sc0 sc1" : "=v"(dB0) : "v"(hpn + 0) : "memory");
      asm volatile("global_load_dwordx4 %0, %1, off sc0 sc1" : "=v"(dB1) : "v"(hpn + 4) : "memory");
      asm volatile("global_load_dwordx4 %0, %1, off sc0 sc1" : "=v"(dB2) : "v"(hpn + 8) : "memory");
    }
    if (j + 1 < NW){
      int ta2 = dir ? (NW - 2 - j) : (j + 1);
      const float* xp2 = xg + (size_t)ta2 * G4 + jbase + fr;
      asm volatile("global_load_dword %0, %1, off" : "=v"(xa0) : "v"(xp2 + (size_t)(q*4+0)*RS) : "memory");
      asm volatile("global_load_dword %0, %1, off" : "=v"(xa1) : "v"(xp2 + (size_t)(q*4+1)*RS) : "memory");
      asm volatile("global_load_dword %0, %1, off" : "=v"(xa2) : "v"(xp2 + (size_t)(q*4+2)*RS) : "memory");
      asm volatile("global_load_dword %0, %1, off" : "=v"(xa3) : "v"(xp2 + (size_t)(q*4+3)*RS) : "memory");
    }
    asm volatile("s_waitcnt lgkmcnt(0)" ::: "memory");
    __builtin_amdgcn_s_barrier();
    __builtin_amdgcn_sched_barrier(0);
    {
      float gi2 = pre[0][eb][ecol], gf2 = pre[1][eb][ecol];
      float gg2 = pre[2][eb][ecol], go2 = pre[3][eb][ecol];
      cA = sigm(gf2) * cA + sigm(gi2) * ftanh(gg2);
      float h = sigm(go2) * ftanh(cA);
      unsigned int hv = (unsigned int)(unsigned short)f2bf(h);
      if (j < NW - 1){
        unsigned int wtag = (hv << 16) | ((unsigned int)(j + 1) & 0xffffu);
        unsigned int* hw = hbD + (size_t)(j & 1) * 16 * HID + eb * HID + cg * WGC + ecol;
        asm volatile("global_store_dword %0, %1, off sc0 sc1" :: "v"(hw), "v"(wtag) : "memory");
      } else {
        short* hc = hcat + ((size_t)eb * NW + t_act) * HH + dir * HID + cg * WGC + ecol;
        asm volatile("global_store_short %0, %1, off" :: "v"(hc), "v"(hv) : "memory");
      }
    }
    //================ tick B: X=1, t=j ================
    if (j == NW - 1) { asm volatile("s_waitcnt vmcnt(1)" ::: "memory"); }
    else             { asm volatile("s_waitcnt vmcnt(5)" ::: "memory"); }
    __builtin_amdgcn_sched_barrier(0);
    if (j > 0){
      unsigned int expect = (unsigned int)j & 0xffffu;
      const unsigned int* hpr = hbD + ((size_t)2 + ((j - 1) & 1)) * 16 * HID + eb * HID + sc;
      for (;;){
        unsigned int bad = TAGBAD(dB0) | TAGBAD(dB1) | TAGBAD(dB2);
        if (__all(bad == 0)) break;
        __builtin_amdgcn_s_sleep(1);
        asm volatile("global_load_dwordx4 %0, %1, off sc0 sc1" : "=v"(dB0) : "v"(hpr + 0) : "memory");
        asm volatile("global_load_dwordx4 %0, %1, off sc0 sc1" : "=v"(dB1) : "v"(hpr + 4) : "memory");
        asm volatile("global_load_dwordx4 %0, %1, off sc0 sc1" : "=v"(dB2) : "v"(hpr + 8) : "memory");
        asm volatile("s_waitcnt vmcnt(0)" ::: "memory");
        __builtin_amdgcn_sched_barrier(0);
      }
      unsigned int pk0 = (dB0[0] >> 16) | (dB0[1] & 0xffff0000u);
      unsigned int pk1 = (dB0[2] >> 16) | (dB0[3] & 0xffff0000u);
      unsigned int pk2 = (dB1[0] >> 16) | (dB1[1] & 0xffff0000u);
      unsigned int pk3 = (dB1[2] >> 16) | (dB1[3] & 0xffff0000u);
      unsigned int pk4 = (dB2[0] >> 16) | (dB2[1] & 0xffff0000u);
      unsigned int pk5 = (dB2[2] >> 16) | (dB2[3] & 0xffff0000u);
      u32x2 w0 = {pk0, pk1}, w1 = {pk2, pk3}, w2 = {pk4, pk5};
      short* dst = &hs[1][eb * HPAD + sc];
      *(u32x2*)(dst)     = w0;
      *(u32x2*)(dst + 4) = w1;
      *(u32x2*)(dst + 8) = w2;
      if (cg == 0){
        int tprev = dir ? (NW - j) : (j - 1);
        short* dh = hcat + ((size_t)(16 + eb) * NW + tprev) * HH + dir * HID + sc;
        asm volatile("global_store_dwordx2 %0, %1, off" :: "v"(dh),     "v"(w0) : "memory");
        asm volatile("global_store_dwordx2 %0, %1, off" :: "v"(dh + 4), "v"(w1) : "memory");
        asm volatile("global_store_dwordx2 %0, %1, off" :: "v"(dh + 8), "v"(w2) : "memory");
      }
    }
    asm volatile("s_waitcnt lgkmcnt(0)" ::: "memory");
    __builtin_amdgcn_s_barrier();
    __builtin_amdgcn_sched_barrier(0);
    f32x4 accb = {}, accb2 = {};
    if (j > 0){
      const short* hrow = &hs[1][fr * HPAD + q * 8];
#pragma unroll
      for (int ks = 0; ks < 6; ++ks)
        accb  = __builtin_amdgcn_mfma_f32_16x16x32_bf16(*(const short8*)(hrow + ks * 32), bfrag[ks], accb, 0, 0, 0);
#pragma unroll
      for (int ks = 6; ks < 12; ++ks)
        accb2 = __builtin_amdgcn_mfma_f32_16x16x32_bf16(*(const short8*)(hrow + ks * 32), bfrag[ks], accb2, 0, 0, 0);
      accb += accb2;
    }
    pre[g][q*4+0][nh*16+fr] = accb[0] + xb0;
    pre[g][q*4+1][nh*16+fr] = accb[1] + xb1;
    pre[g][q*4+2][nh*16+fr] = accb[2] + xb2;
    pre[g][q*4+3][nh*16+fr] = accb[3] + xb3;
    // mid: h-load for next tick A (h(X0,j)) FIRST, then xg for next tick B (X1,j+1)
    if (j + 1 < NW){
      const unsigned int* hpn = hbD + (size_t)(j & 1) * 16 * HID + eb * HID + sc;  // X=0 slots
      asm volatile("global_load_dwordx4 %0, %1, off sc0 sc1" : "=v"(dA0) : "v"(hpn + 0) : "memory");
      asm volatile("global_load_dwordx4 %0, %1, off sc0 sc1" : "=v"(dA1) : "v"(hpn + 4) : "memory");
      asm volatile("global_load_dwordx4 %0, %1, off sc0 sc1" : "=v"(dA2) : "v"(hpn + 8) : "memory");
      int ta2 = dir ? (NW - 2 - j) : (j + 1);
      const float* xp2 = xg + (size_t)ta2 * G4 + jbase + fr + (size_t)16 * RS;
      asm volatile("global_load_dword %0, %1, off" : "=v"(xb0) : "v"(xp2 + (size_t)(q*4+0)*RS) : "memory");
      asm volatile("global_load_dword %0, %1, off" : "=v"(xb1) : "v"(xp2 + (size_t)(q*4+1)*RS) : "memory");
      asm volatile("global_load_dword %0, %1, off" : "=v"(xb2) : "v"(xp2 + (size_t)(q*4+2)*RS) : "memory");
      asm volatile("global_load_dword %0, %1, off" : "=v"(xb3) : "v"(xp2 + (size_t)(q*4+3)*RS) : "memory");
    }
    asm volatile("s_waitcnt lgkmcnt(0)" ::: "memory");
    __builtin_amdgcn_s_barrier();
    __builtin_amdgcn_sched_barrier(0);
    {
      float gi2 = pre[0][eb][ecol], gf2 = pre[1][eb][ecol];
      float gg2 = pre[2][eb][ecol], go2 = pre[3][eb][ecol];
      cB = sigm(gf2) * cB + sigm(gi2) * ftanh(gg2);
      float h = sigm(go2) * ftanh(cB);
      unsigned int hv = (unsigned int)(unsigned short)f2bf(h);
      if (j < NW - 1){
        unsigned int wtag = (hv << 16) | ((unsigned int)(j + 1) & 0xffffu);
        unsigned int* hw = hbD + ((size_t)2 + (j & 1)) * 16 * HID + eb * HID + cg * WGC + ecol;
        asm volatile("global_store_dword %0, %1, off sc0 sc1" :: "v"(hw), "v"(wtag) : "memory");
      } else {
        short* hc = hcat + ((size_t)(16 + eb) * NW + t_act) * HH + dir * HID + cg * WGC + ecol;
        asm volatile("global_store_short %0, %1, off" :: "v"(hc), "v"(hv) : "memory");
      }
    }
  }
}

// ---------------- gate MLP + softmax (per batch row) ----------------
__global__ __launch_bounds__(256) void k_gate(const float* __restrict__ tok,
                                              const int* __restrict__ lids,
                                              const float* __restrict__ ltab,
                                              const float* __restrict__ W1,
                                              const float* __restrict__ b1v,
                                              const float* __restrict__ W2,
                                              const float* __restrict__ b2v,
                                              float* __restrict__ gate){
  __shared__ float gin[GIN];
  __shared__ float hid[HH];
  __shared__ float pr[EE];
  int b = blockIdx.x, tid = threadIdx.x;
  int lid = lids[b];
  for (int i = tid; i < GIN; i += 256)
    gin[i] = (i < HH) ? tok[(size_t)b * LL * HH + i] : ltab[lid * DLL + (i - HH)];
  __syncthreads();
  for (int j = tid; j < HH; j += 256){
    float a = b1v[j];
    const float* wr = W1 + (size_t)j * GIN;
    for (int k = 0; k < GIN; ++k) a += gin[k] * wr[k];
    hid[j] = fmaxf(a, 0.f);
  }
  __syncthreads();
  int wv = tid >> 6, lane = tid & 63;
  if (wv < EE){
    float p = 0.f;
    for (int k = lane; k < HH; k += 64) p += hid[k] * W2[wv * HH + k];
#pragma unroll
    for (int off = 32; off; off >>= 1) p += __shfl_down(p, off);
    if (lane == 0) pr[wv] = p + b2v[wv];
  }
  __syncthreads();
  if (tid == 0){
    float mx = fmaxf(fmaxf(pr[0], pr[1]), fmaxf(pr[2], pr[3]));
    float s = 0.f, ex[EE];
    for (int e2 = 0; e2 < EE; ++e2){ ex[e2] = __expf(pr[e2] - mx); s += ex[e2]; }
    for (int e2 = 0; e2 < EE; ++e2) gate[b * EE + e2] = ex[e2] / s;
  }
}

// ---------------- head precompute: A = headW @ proj_W, c = headW.proj_b + head_b ----------------
__global__ __launch_bounds__(256) void k_headpre(const float* __restrict__ efW,
                                                 const float* __restrict__ efb,
                                                 const float* __restrict__ edW,
                                                 const float* __restrict__ edb,
                                                 const float* __restrict__ projW,
                                                 const float* __restrict__ projb,
                                                 float* __restrict__ Acomb,
                                                 float* __restrict__ Ccomb){
  int head = blockIdx.x >> 2, e2 = blockIdx.x & 3, tid = threadIdx.x;
  const float* Wv = head ? edW : efW;
  const float* bv = head ? edb : efb;
  __shared__ float wrow[HH];
  for (int i = tid; i < HH; i += 256) wrow[i] = Wv[e2 * HH + i];
  __syncthreads();
  for (int c = tid; c < HH; c += 256){
    float a = 0.f;
    for (int h2 = 0; h2 < HH; ++h2) a += wrow[h2] * projW[(size_t)h2 * HH + c];
    Acomb[(head * 4 + e2) * HH + c] = a;
  }
  int wv = tid >> 6, lane = tid & 63;
  if (wv == 0){
    float p = 0.f;
    for (int k = lane; k < HH; k += 64) p += wrow[k] * projb[k];
#pragma unroll
    for (int off = 32; off; off >>= 1) p += __shfl_down(p, off);
    if (lane == 0) Ccomb[head * 4 + e2] = p + bv[e2];
  }
}

// ---------------- fused expert heads: out = sum_e gate * (hcat.A_e + c_e) ----------------
__global__ __launch_bounds__(256) void k_heads(const short* __restrict__ hcat,
                                               const float* __restrict__ Acomb,
                                               const float* __restrict__ Ccomb,
                                               const float* __restrict__ gate,
                                               float* __restrict__ outp){
  __shared__ float Al[8 * HH];   // 24 KB
  int tid = threadIdx.x;
  for (int i = tid; i < 8 * HH; i += 256) Al[i] = Acomb[i];
  __syncthreads();
  int wv = tid >> 6, lane = tid & 63;
  int bw = blockIdx.x * 4 + wv;        // = b*512 + w
  const short* hr = hcat + (size_t)bw * HH;
  float hv[12];
#pragma unroll
  for (int j = 0; j < 12; ++j) hv[j] = bf2f(hr[lane + 64 * j]);
  float dsum[8];
#pragma unroll
  for (int v = 0; v < 8; ++v){
    float p = 0.f;
#pragma unroll
    for (int j = 0; j < 12; ++j) p += hv[j] * Al[v * HH + lane + 64 * j];
#pragma unroll
    for (int off = 32; off; off >>= 1) p += __shfl_xor(p, off);
    dsum[v] = p;
  }
  if (lane == 0){
    int b = bw >> 9;
    float fx = 0.f, du = 0.f;
#pragma unroll
    for (int e2 = 0; e2 < 4; ++e2){
      float g = gate[b * 4 + e2];
      fx += g * (dsum[e2]     + Ccomb[e2]);
      du += g * (dsum[4 + e2] + Ccomb[4 + e2]);
    }
    outp[bw] = fx;
    outp[BB * NW + bw] = du;
  }
}

extern "C" void kernel_launch(void* const* d_in, const int* in_sizes, int n_in,
                              void* d_out, int out_size, void* d_ws, size_t ws_size,
                              hipStream_t stream){
  const float* tok   = (const float*)d_in[0];
  const int*   wmap  = (const int*)d_in[1];
  const int*   lids  = (const int*)d_in[2];
  const float* Wih_f = (const float*)d_in[3];
  const float* Whh_f = (const float*)d_in[4];
  const float* bih_f = (const float*)d_in[5];
  const float* bhh_f = (const float*)d_in[6];
  const float* Wih_b = (const float*)d_in[7];
  const float* Whh_b = (const float*)d_in[8];
  const float* bih_b = (const float*)d_in[9];
  const float* bhh_b = (const float*)d_in[10];
  const float* projW = (const float*)d_in[11];
  const float* projb = (const float*)d_in[12];
  const float* ltab  = (const float*)d_in[13];
  const float* gW1   = (const float*)d_in[14];
  const float* gb1   = (const float*)d_in[15];
  const float* gW2   = (const float*)d_in[16];
  const float* gb2   = (const float*)d_in[17];
  const float* efW   = (const float*)d_in[18];
  const float* efb   = (const float*)d_in[19];
  const float* edW   = (const float*)d_in[20];
  const float* edb   = (const float*)d_in[21];
  float* outp = (float*)d_out;

  char* ws = (char*)d_ws;
  size_t off = 0;
  auto alloc = [&](size_t bytes) -> char* {
    char* p = ws + off;
    off = (off + bytes + 255) & ~(size_t)255;
    return p;
  };
  short* we_bf   = (short*)alloc((size_t)BB * NW * HH * 2);
  short* wihf_bf = (short*)alloc((size_t)G4 * HH * 2);
  short* wihb_bf = (short*)alloc((size_t)G4 * HH * 2);
  short* whhf_bf = (short*)alloc((size_t)G4 * HID * 2);
  short* whhb_bf = (short*)alloc((size_t)G4 * HID * 2);
  float* xg_f    = (float*)alloc((size_t)BB * NW * G4 * 4);
  float* xg_b    = (float*)alloc((size_t)BB * NW * G4 * 4);
  short* hcat    = (short*)alloc((size_t)BB * NW * HH * 2);
  unsigned int* hbuf = (unsigned int*)alloc((size_t)2 * 2 * 2 * 16 * HID * 4);  // tagged
  float* gateb   = (float*)alloc((size_t)BB * EE * 4);
  float* Acomb   = (float*)alloc((size_t)8 * HH * 4);
  float* Ccomb   = (float*)alloc((size_t)8 * 4);

  k_f2bf<<<1024, 256, 0, stream>>>(Wih_f, wihf_bf, G4 * HH);
  k_f2bf<<<1024, 256, 0, stream>>>(Wih_b, wihb_bf, G4 * HH);
  k_f2bf<<<512, 256, 0, stream>>>(Whh_f, whhf_bf, G4 * HID);
  k_f2bf<<<512, 256, 0, stream>>>(Whh_b, whhb_bf, G4 * HID);
  k_segmean<<<BB * NW, 256, 0, stream>>>(tok, wmap, we_bf);
  k_gemm_bt<<<(BB * NW / 128) * (G4 / 128), 256, 0, stream>>>(we_bf, wihf_bf, bih_f, bhh_f, xg_f, BB * NW, G4, HH);
  k_gemm_bt<<<(BB * NW / 128) * (G4 / 128), 256, 0, stream>>>(we_bf, wihb_bf, bih_b, bhh_b, xg_b, BB * NW, G4, HH);
  k_gate<<<BB, 256, 0, stream>>>(tok, lids, ltab, gW1, gb1, gW2, gb2, gateb);
  k_headpre<<<8, 256, 0, stream>>>(efW, efb, edW, edb, projW, projb, Acomb, Ccomb);
  k_lstm<<<2 * CWG, 512, 0, stream>>>(xg_f, xg_b, whhf_bf, whhb_bf, hbuf, hcat);
  k_heads<<<(BB * NW) / 4, 256, 0, stream>>>(hcat, Acomb, Ccomb, gateb, outp);
}